// Round 1
// baseline (818.123 us; speedup 1.0000x reference)
//
#include <hip/hip_runtime.h>

#define EPS   1e-5f
#define SLOPE 0.01f

// ---------------------------------------------------------------------------
// Workspace layout (float offsets). Total 40,170,944 floats = 160,683,776 B.
// ---------------------------------------------------------------------------
#define WS_H1   0L            // h1   NHWC (64,56,56,96)        19267584
#define WS_S    19267584L     // S    [n=12544][k=1536]         19267584
#define WS_OFF  38535168L     // off  NHWC (64,14,14,32)          401408
#define WS_WT   38936576L     // Wt   [k=1536][oc=768] (scaled)  1179648
#define WS_WT4  40116224L     // Wt4  [g=384][oc=32][4]            49152
#define WS_W1T  40165376L     // w1t  [k=48][c=96]                  4608
#define WS_S1   40169984L     // bn1 scale [96]
#define WS_T1   40170080L     // bn1 bias  [96]
#define WS_T2   40170176L     // fused dcn_b+bn2 bias [768]

// ---------------------------------------------------------------------------
// K0: weight prep. Folds bn scales/biases into weights so downstream kernels
// are pure GEMM + leaky.
//   Wt[k][oc]  = dcn_w[oc][c][kk] * inv2[oc],  k = kk*96 + c
//   Wt4[g][oc][j] = off_w[oc][c][khw],        k = g*4+j = khw*96 + c
//   w1t[k][c]  = stem_w[c][k]                 (k = ci*16+kh*4+kw)
// ---------------------------------------------------------------------------
__global__ __launch_bounds__(256) void k0_prep(
    const float* __restrict__ stem_w, const float* __restrict__ stem_b,
    const float* __restrict__ bn1_g,  const float* __restrict__ bn1_b,
    const float* __restrict__ bn1_m,  const float* __restrict__ bn1_v,
    const float* __restrict__ off_w,  const float* __restrict__ dcn_w,
    const float* __restrict__ dcn_b,  const float* __restrict__ bn2_g,
    const float* __restrict__ bn2_b,  const float* __restrict__ bn2_m,
    const float* __restrict__ bn2_v,  float* __restrict__ ws)
{
    long i = (long)blockIdx.x * 256 + threadIdx.x;
    if (i < 1179648L) {                       // Wt
        int k  = (int)(i / 768), oc = (int)(i % 768);
        int kk = k / 96, c = k % 96;
        float inv2 = bn2_g[oc] * rsqrtf(bn2_v[oc] + EPS);
        ws[WS_WT + i] = dcn_w[oc * 1536 + c * 16 + kk] * inv2;
    } else if (i < 1228800L) {                // Wt4
        int i2 = (int)(i - 1179648L);
        int g = i2 >> 7, oc = (i2 >> 2) & 31, j = i2 & 3;
        int khw = g / 24, c = (g % 24) * 4 + j;
        ws[WS_WT4 + i2] = off_w[oc * 1536 + c * 16 + khw];
    } else if (i < 1233408L) {                // w1t
        int i3 = (int)(i - 1228800L);
        int k = i3 / 96, c = i3 % 96;
        ws[WS_W1T + i3] = stem_w[c * 48 + k];
    } else if (i < 1233504L) {                // s1
        int c = (int)(i - 1233408L);
        ws[WS_S1 + c] = bn1_g[c] * rsqrtf(bn1_v[c] + EPS);
    } else if (i < 1233600L) {                // t1
        int c = (int)(i - 1233504L);
        float s = bn1_g[c] * rsqrtf(bn1_v[c] + EPS);
        ws[WS_T1 + c] = stem_b[c] * s + bn1_b[c] - bn1_m[c] * s;
    } else if (i < 1234368L) {                // t2
        int oc = (int)(i - 1233600L);
        float inv2 = bn2_g[oc] * rsqrtf(bn2_v[oc] + EPS);
        ws[WS_T2 + oc] = dcn_b[oc] * inv2 + bn2_b[oc] - bn2_m[oc] * inv2;
    }
}

// ---------------------------------------------------------------------------
// K1: stem conv (stride 4, kernel 4, non-overlapping) + bn1 + leaky.
// Output h1 in NHWC (96 channels contiguous) for later coalesced sampling.
// Block = (oy, b); LDS holds the 4-row input strip + transposed weights.
// 4ox x 4c register microtile.
// ---------------------------------------------------------------------------
__global__ __launch_bounds__(256) void k1_stem(
    const float* __restrict__ x, const float* __restrict__ w1t,
    const float* __restrict__ s1, const float* __restrict__ t1,
    float* __restrict__ h1)
{
    const int oy = blockIdx.x;   // 0..55
    const int b  = blockIdx.y;   // 0..63
    const int tid = threadIdx.x;

    __shared__ float xs[3 * 4 * 224];   // [ci][kh][xx]
    __shared__ float wsh[48 * 100];     // [k][c], row stride 100 (pad)
    __shared__ float s1s[96], t1s[96];

    for (int i = tid; i < 2688; i += 256) {
        int ci = i / 896, r = i % 896;
        int kh = r / 224, xx = r % 224;
        xs[i] = x[((long)(b * 3 + ci) * 224 + oy * 4 + kh) * 224 + xx];
    }
    for (int i = tid; i < 4608; i += 256) {
        int k = i / 96, c = i % 96;
        wsh[k * 100 + c] = w1t[i];
    }
    if (tid < 96) { s1s[tid] = s1[tid]; t1s[tid] = t1[tid]; }
    __syncthreads();

    // 14 oxg * 24 cg = 336 units; each unit = 4 ox x 4 c outputs.
    for (int u = tid; u < 336; u += 256) {
        int oxg = u / 24, cg = u % 24;
        float acc[4][4] = {};
#pragma unroll
        for (int ci = 0; ci < 3; ci++) {
#pragma unroll
            for (int kh = 0; kh < 4; kh++) {
                const float* xrow = &xs[(ci * 4 + kh) * 224 + oxg * 16];
                float4 xv[4], wv[4];
#pragma unroll
                for (int o = 0; o < 4; o++) xv[o] = *(const float4*)&xrow[o * 4];
#pragma unroll
                for (int kw = 0; kw < 4; kw++)
                    wv[kw] = *(const float4*)&wsh[(ci * 16 + kh * 4 + kw) * 100 + cg * 4];
#pragma unroll
                for (int kw = 0; kw < 4; kw++) {
                    const float* wf = (const float*)&wv[kw];
#pragma unroll
                    for (int o = 0; o < 4; o++) {
                        float xv_s = ((const float*)&xv[o])[kw];
#pragma unroll
                        for (int cc = 0; cc < 4; cc++)
                            acc[o][cc] += xv_s * wf[cc];
                    }
                }
            }
        }
#pragma unroll
        for (int o = 0; o < 4; o++) {
            float4 r;
            float* rp = (float*)&r;
#pragma unroll
            for (int cc = 0; cc < 4; cc++) {
                int c = cg * 4 + cc;
                float v = acc[o][cc] * s1s[c] + t1s[c];
                rp[cc] = v >= 0.f ? v : SLOPE * v;
            }
            *(float4*)&h1[((long)((b * 56 + oy) * 56) + oxg * 4 + o) * 96 + cg * 4] = r;
        }
    }
}

// ---------------------------------------------------------------------------
// K2: offset conv (stride 4, kernel 4) + off_b. Thread computes 4 oc for one
// (b,oy,ox). K-loop float4 over channels; Wt4 pre-swizzled for coalescing.
// Output off in NHWC (64,14,14,32).
// ---------------------------------------------------------------------------
__global__ __launch_bounds__(256) void k2_off(
    const float* __restrict__ h1, const float* __restrict__ wt4,
    const float* __restrict__ off_b, float* __restrict__ off)
{
    int gid = blockIdx.x * 256 + threadIdx.x;    // 100352 total
    int b   = gid / 1568;
    int r   = gid % 1568;
    int oy  = r / 112;
    int r2  = r % 112;
    int ox  = r2 / 8;
    int ocq = r2 % 8;

    const float* hb = h1 + ((long)(b * 56 + oy * 4) * 56 + ox * 4) * 96;
    float acc[4] = {};
    int g = 0;
#pragma unroll
    for (int khw = 0; khw < 16; khw++) {
        int kh = khw >> 2, kw = khw & 3;
        const float* hrow = hb + (kh * 56 + kw) * 96;
        for (int c4 = 0; c4 < 24; c4++, g++) {
            float4 v = *(const float4*)&hrow[c4 * 4];
            const float4* wp = (const float4*)&wt4[g * 128];
#pragma unroll
            for (int q = 0; q < 4; q++) {
                float4 w = wp[ocq * 4 + q];
                acc[q] += v.x * w.x + v.y * w.y + v.z * w.z + v.w * w.w;
            }
        }
    }
    float4 o4;
    float* op = (float*)&o4;
#pragma unroll
    for (int q = 0; q < 4; q++) op[q] = acc[q] + off_b[ocq * 4 + q];
    *(float4*)&off[((long)((b * 14 + oy) * 14 + ox)) * 32 + ocq * 4] = o4;
}

// ---------------------------------------------------------------------------
// K3: bilinear sampling -> S[n][k], k = kk*96 + c. Block = (p, b), 384 thr:
// thread = (kk 0..15, c4 0..23). Gathers are 24-lane contiguous runs of 96
// floats thanks to NHWC h1.
// ---------------------------------------------------------------------------
__global__ __launch_bounds__(384) void k3_sample(
    const float* __restrict__ h1, const float* __restrict__ off,
    float* __restrict__ S)
{
    const int p = blockIdx.x;     // 0..195
    const int b = blockIdx.y;     // 0..63
    const int y = p / 14, xo = p % 14;
    const int tid = threadIdx.x;
    const int c4 = tid % 24, kk = tid / 24;
    const int kh = kk >> 2, kw = kk & 3;

    const float* ob = off + ((long)((b * 14 + y) * 14 + xo)) * 32;
    float dy = ob[kk * 2];
    float dx = ob[kk * 2 + 1];

    float py = (float)(y * 4 + kh) + dy;
    float px = (float)(xo * 4 + kw) + dx;
    float y0f = floorf(py), x0f = floorf(px);
    float wy = py - y0f, wx = px - x0f;
    int y0 = (int)y0f, x0 = (int)x0f;
    int y1 = y0 + 1,  x1 = x0 + 1;

    float my0 = (y0 >= 0 && y0 < 56) ? 1.f : 0.f;
    float my1 = (y1 >= 0 && y1 < 56) ? 1.f : 0.f;
    float mx0 = (x0 >= 0 && x0 < 56) ? 1.f : 0.f;
    float mx1 = (x1 >= 0 && x1 < 56) ? 1.f : 0.f;
    int y0c = min(max(y0, 0), 55), y1c = min(max(y1, 0), 55);
    int x0c = min(max(x0, 0), 55), x1c = min(max(x1, 0), 55);

    const float* hb = h1 + (long)b * 56 * 56 * 96 + c4 * 4;
    float4 v00 = *(const float4*)&hb[(y0c * 56 + x0c) * 96];
    float4 v01 = *(const float4*)&hb[(y0c * 56 + x1c) * 96];
    float4 v10 = *(const float4*)&hb[(y1c * 56 + x0c) * 96];
    float4 v11 = *(const float4*)&hb[(y1c * 56 + x1c) * 96];

    float w00 = my0 * mx0 * (1.f - wy) * (1.f - wx);
    float w01 = my0 * mx1 * (1.f - wy) * wx;
    float w10 = my1 * mx0 * wy * (1.f - wx);
    float w11 = my1 * mx1 * wy * wx;

    float4 rr;
    rr.x = v00.x * w00 + v01.x * w01 + v10.x * w10 + v11.x * w11;
    rr.y = v00.y * w00 + v01.y * w01 + v10.y * w10 + v11.y * w11;
    rr.z = v00.z * w00 + v01.z * w01 + v10.z * w10 + v11.z * w11;
    rr.w = v00.w * w00 + v01.w * w01 + v10.w * w10 + v11.w * w11;

    long n = (long)b * 196 + p;
    *(float4*)&S[n * 1536 + kk * 96 + c4 * 4] = rr;
}

// ---------------------------------------------------------------------------
// K4: GEMM C[n][oc] = S[n][k] * Wt[k][oc], N=12544, M=768, K=1536.
// 128x128 block tile, BK=16, 8x8 register microtile, 256 threads.
// Epilogue: leaky(acc + t2[oc]); C written directly to d_out (already the
// transposed (B,P,C) layout).
// ---------------------------------------------------------------------------
__global__ __launch_bounds__(256) void k4_gemm(
    const float* __restrict__ S, const float* __restrict__ Wt,
    const float* __restrict__ t2, float* __restrict__ out)
{
    const int oc0 = blockIdx.x * 128;   // 6 tiles (oc fast: S tile shared in L2)
    const int n0  = blockIdx.y * 128;   // 98 tiles
    const int tid = threadIdx.x;
    const int tx = tid & 15, ty = tid >> 4;

    __shared__ float As[16][132];   // [k][n]
    __shared__ float Bs[16][132];   // [k][oc]

    float acc[8][8] = {};

    for (int k0 = 0; k0 < 1536; k0 += 16) {
        // stage A (transpose to [k][n])
#pragma unroll
        for (int i = tid; i < 512; i += 256) {
            int rrow = i >> 2, kq = i & 3;
            float4 v = *(const float4*)&S[(long)(n0 + rrow) * 1536 + k0 + kq * 4];
            As[kq * 4 + 0][rrow] = v.x;
            As[kq * 4 + 1][rrow] = v.y;
            As[kq * 4 + 2][rrow] = v.z;
            As[kq * 4 + 3][rrow] = v.w;
        }
        // stage B (already [k][oc])
#pragma unroll
        for (int i = tid; i < 512; i += 256) {
            int kl = i >> 5, ocq = i & 31;
            *(float4*)&Bs[kl][ocq * 4] =
                *(const float4*)&Wt[(long)(k0 + kl) * 768 + oc0 + ocq * 4];
        }
        __syncthreads();

#pragma unroll
        for (int k = 0; k < 16; k++) {
            float4 a0 = *(const float4*)&As[k][ty * 8];
            float4 a1 = *(const float4*)&As[k][ty * 8 + 4];
            float4 b0 = *(const float4*)&Bs[k][tx * 8];
            float4 b1 = *(const float4*)&Bs[k][tx * 8 + 4];
            float a[8] = {a0.x, a0.y, a0.z, a0.w, a1.x, a1.y, a1.z, a1.w};
            float bb[8] = {b0.x, b0.y, b0.z, b0.w, b1.x, b1.y, b1.z, b1.w};
#pragma unroll
            for (int ii = 0; ii < 8; ii++)
#pragma unroll
                for (int jj = 0; jj < 8; jj++)
                    acc[ii][jj] += a[ii] * bb[jj];
        }
        __syncthreads();
    }

    // epilogue: leaky(acc + t2)
    float4 tA = *(const float4*)&t2[oc0 + tx * 8];
    float4 tB = *(const float4*)&t2[oc0 + tx * 8 + 4];
    float tb[8] = {tA.x, tA.y, tA.z, tA.w, tB.x, tB.y, tB.z, tB.w};
#pragma unroll
    for (int ii = 0; ii < 8; ii++) {
        long n = n0 + ty * 8 + ii;
        float4 r0, r1;
        float* p0 = (float*)&r0;
        float* p1 = (float*)&r1;
#pragma unroll
        for (int jj = 0; jj < 4; jj++) {
            float v = acc[ii][jj] + tb[jj];
            p0[jj] = v >= 0.f ? v : SLOPE * v;
            float u = acc[ii][jj + 4] + tb[jj + 4];
            p1[jj] = u >= 0.f ? u : SLOPE * u;
        }
        *(float4*)&out[n * 768 + oc0 + tx * 8]     = r0;
        *(float4*)&out[n * 768 + oc0 + tx * 8 + 4] = r1;
    }
}

// ---------------------------------------------------------------------------
extern "C" void kernel_launch(void* const* d_in, const int* in_sizes, int n_in,
                              void* d_out, int out_size, void* d_ws, size_t ws_size,
                              hipStream_t stream)
{
    const float* x      = (const float*)d_in[0];
    const float* stem_w = (const float*)d_in[1];
    const float* stem_b = (const float*)d_in[2];
    const float* bn1_g  = (const float*)d_in[3];
    const float* bn1_b  = (const float*)d_in[4];
    const float* bn1_m  = (const float*)d_in[5];
    const float* bn1_v  = (const float*)d_in[6];
    const float* off_w  = (const float*)d_in[7];
    const float* off_b  = (const float*)d_in[8];
    const float* dcn_w  = (const float*)d_in[9];
    const float* dcn_b  = (const float*)d_in[10];
    const float* bn2_g  = (const float*)d_in[11];
    const float* bn2_b  = (const float*)d_in[12];
    const float* bn2_m  = (const float*)d_in[13];
    const float* bn2_v  = (const float*)d_in[14];

    float* ws  = (float*)d_ws;        // needs 160,683,776 bytes
    float* out = (float*)d_out;

    float* h1  = ws + WS_H1;
    float* S   = ws + WS_S;
    float* off = ws + WS_OFF;
    float* Wt  = ws + WS_WT;
    float* wt4 = ws + WS_WT4;
    float* w1t = ws + WS_W1T;
    float* s1  = ws + WS_S1;
    float* t1  = ws + WS_T1;
    float* t2  = ws + WS_T2;

    k0_prep<<<4823, 256, 0, stream>>>(stem_w, stem_b, bn1_g, bn1_b, bn1_m, bn1_v,
                                      off_w, dcn_w, dcn_b, bn2_g, bn2_b, bn2_m,
                                      bn2_v, ws);
    k1_stem<<<dim3(56, 64), 256, 0, stream>>>(x, w1t, s1, t1, h1);
    k2_off<<<392, 256, 0, stream>>>(h1, wt4, off_b, off);
    k3_sample<<<dim3(196, 64), 384, 0, stream>>>(h1, off, S);
    k4_gemm<<<dim3(6, 98), 256, 0, stream>>>(S, Wt, t2, out);
}

// Round 2
// 420.278 us; speedup vs baseline: 1.9466x; 1.9466x over previous
//
#include <hip/hip_runtime.h>

#define EPS   1e-5f
#define SLOPE 0.01f

// ---------------------------------------------------------------------------
// Workspace layout (float offsets). Total 29,947,328 floats = 119.8 MB.
// ---------------------------------------------------------------------------
#define WS_H1   0L            // h1   NHWC f32 (64,56,56,96)    19267584
#define WS_OFF  19267584L     // off  NHWC f32 (64,14,14,32)      401408
#define WS_WT4  19668992L     // wt4  f32 [g=384][oc=32][4]        49152
#define WS_W1T  19718144L     // w1t  f32 [k=48][c=96]              4608
#define WS_S1   19722752L     // bn1 scale f32 [96]
#define WS_T1   19722848L     // bn1 bias  f32 [96]
#define WS_T2   19722944L     // fused dcn_b+bn2 bias f32 [768]
#define WS_SB   19723712L     // S    bf16 [n=12544][k=1536]  (9633792 floats)
#define WS_WTB  29357504L     // Wtb  bf16 [oc=768][k=1536]   (589824 floats)

__device__ __forceinline__ unsigned short f2bf(float f) {
    unsigned int u = __builtin_bit_cast(unsigned int, f);
    u += 0x7fffu + ((u >> 16) & 1u);
    return (unsigned short)(u >> 16);
}

// ---------------------------------------------------------------------------
// K0: weight prep.
//   Wtb[oc][k] = bf16( dcn_w[oc][c][kk] * inv2[oc] ),  k = kk*96 + c  (B^T!)
//   wt4[g][oc][j] = off_w[oc][c][khw],  k = g*4+j = khw*96 + c
//   w1t[k][c]  = stem_w[c][k]           (k = ci*16+kh*4+kw)
// ---------------------------------------------------------------------------
__global__ __launch_bounds__(256) void k0_prep(
    const float* __restrict__ stem_w, const float* __restrict__ stem_b,
    const float* __restrict__ bn1_g,  const float* __restrict__ bn1_b,
    const float* __restrict__ bn1_m,  const float* __restrict__ bn1_v,
    const float* __restrict__ off_w,  const float* __restrict__ dcn_w,
    const float* __restrict__ dcn_b,  const float* __restrict__ bn2_g,
    const float* __restrict__ bn2_b,  const float* __restrict__ bn2_m,
    const float* __restrict__ bn2_v,  float* __restrict__ ws)
{
    long i = (long)blockIdx.x * 256 + threadIdx.x;
    unsigned short* Wtb = (unsigned short*)(ws + WS_WTB);
    if (i < 1179648L) {                       // Wtb  (bf16, [oc][k])
        int oc = (int)(i / 1536), k = (int)(i % 1536);
        int kk = k / 96, c = k % 96;
        float inv2 = bn2_g[oc] * rsqrtf(bn2_v[oc] + EPS);
        Wtb[i] = f2bf(dcn_w[oc * 1536 + c * 16 + kk] * inv2);
    } else if (i < 1228800L) {                // wt4
        int i2 = (int)(i - 1179648L);
        int g = i2 >> 7, oc = (i2 >> 2) & 31, j = i2 & 3;
        int khw = g / 24, c = (g % 24) * 4 + j;
        ws[WS_WT4 + i2] = off_w[oc * 1536 + c * 16 + khw];
    } else if (i < 1233408L) {                // w1t
        int i3 = (int)(i - 1228800L);
        int k = i3 / 96, c = i3 % 96;
        ws[WS_W1T + i3] = stem_w[c * 48 + k];
    } else if (i < 1233504L) {                // s1
        int c = (int)(i - 1233408L);
        ws[WS_S1 + c] = bn1_g[c] * rsqrtf(bn1_v[c] + EPS);
    } else if (i < 1233600L) {                // t1
        int c = (int)(i - 1233504L);
        float s = bn1_g[c] * rsqrtf(bn1_v[c] + EPS);
        ws[WS_T1 + c] = stem_b[c] * s + bn1_b[c] - bn1_m[c] * s;
    } else if (i < 1234368L) {                // t2
        int oc = (int)(i - 1233600L);
        float inv2 = bn2_g[oc] * rsqrtf(bn2_v[oc] + EPS);
        ws[WS_T2 + oc] = dcn_b[oc] * inv2 + bn2_b[oc] - bn2_m[oc] * inv2;
    }
}

// ---------------------------------------------------------------------------
// K1: stem conv (stride 4 == kernel 4, non-overlapping) + bn1 + leaky.
// Output h1 NHWC f32.
// ---------------------------------------------------------------------------
__global__ __launch_bounds__(256) void k1_stem(
    const float* __restrict__ x, const float* __restrict__ w1t,
    const float* __restrict__ s1, const float* __restrict__ t1,
    float* __restrict__ h1)
{
    const int oy = blockIdx.x;   // 0..55
    const int b  = blockIdx.y;   // 0..63
    const int tid = threadIdx.x;

    __shared__ float xs[3 * 4 * 224];   // [ci][kh][xx]
    __shared__ float wsh[48 * 100];     // [k][c], pad stride 100
    __shared__ float s1s[96], t1s[96];

    for (int i = tid; i < 2688; i += 256) {
        int ci = i / 896, r = i % 896;
        int kh = r / 224, xx = r % 224;
        xs[i] = x[((long)(b * 3 + ci) * 224 + oy * 4 + kh) * 224 + xx];
    }
    for (int i = tid; i < 4608; i += 256) {
        int k = i / 96, c = i % 96;
        wsh[k * 100 + c] = w1t[i];
    }
    if (tid < 96) { s1s[tid] = s1[tid]; t1s[tid] = t1[tid]; }
    __syncthreads();

    for (int u = tid; u < 336; u += 256) {   // 14 oxg * 24 cg
        int oxg = u / 24, cg = u % 24;
        float acc[4][4] = {};
#pragma unroll
        for (int ci = 0; ci < 3; ci++) {
#pragma unroll
            for (int kh = 0; kh < 4; kh++) {
                const float* xrow = &xs[(ci * 4 + kh) * 224 + oxg * 16];
                float4 xv[4], wv[4];
#pragma unroll
                for (int o = 0; o < 4; o++) xv[o] = *(const float4*)&xrow[o * 4];
#pragma unroll
                for (int kw = 0; kw < 4; kw++)
                    wv[kw] = *(const float4*)&wsh[(ci * 16 + kh * 4 + kw) * 100 + cg * 4];
#pragma unroll
                for (int kw = 0; kw < 4; kw++) {
                    const float* wf = (const float*)&wv[kw];
#pragma unroll
                    for (int o = 0; o < 4; o++) {
                        float xv_s = ((const float*)&xv[o])[kw];
#pragma unroll
                        for (int cc = 0; cc < 4; cc++)
                            acc[o][cc] += xv_s * wf[cc];
                    }
                }
            }
        }
#pragma unroll
        for (int o = 0; o < 4; o++) {
            float4 r;
            float* rp = (float*)&r;
#pragma unroll
            for (int cc = 0; cc < 4; cc++) {
                int c = cg * 4 + cc;
                float v = acc[o][cc] * s1s[c] + t1s[c];
                rp[cc] = v >= 0.f ? v : SLOPE * v;
            }
            *(float4*)&h1[((long)((b * 56 + oy) * 56) + oxg * 4 + o) * 96 + cg * 4] = r;
        }
    }
}

// ---------------------------------------------------------------------------
// K2: offset conv (stride 4, kernel 4) + off_b. NHWC off (64,14,14,32).
// ---------------------------------------------------------------------------
__global__ __launch_bounds__(256) void k2_off(
    const float* __restrict__ h1, const float* __restrict__ wt4,
    const float* __restrict__ off_b, float* __restrict__ off)
{
    int gid = blockIdx.x * 256 + threadIdx.x;    // 100352 total
    int b   = gid / 1568;
    int r   = gid % 1568;
    int oy  = r / 112;
    int r2  = r % 112;
    int ox  = r2 / 8;
    int ocq = r2 % 8;

    const float* hb = h1 + ((long)(b * 56 + oy * 4) * 56 + ox * 4) * 96;
    float acc[4] = {};
    int g = 0;
#pragma unroll
    for (int khw = 0; khw < 16; khw++) {
        int kh = khw >> 2, kw = khw & 3;
        const float* hrow = hb + (kh * 56 + kw) * 96;
        for (int c4 = 0; c4 < 24; c4++, g++) {
            float4 v = *(const float4*)&hrow[c4 * 4];
            const float4* wp = (const float4*)&wt4[g * 128];
#pragma unroll
            for (int q = 0; q < 4; q++) {
                float4 w = wp[ocq * 4 + q];
                acc[q] += v.x * w.x + v.y * w.y + v.z * w.z + v.w * w.w;
            }
        }
    }
    float4 o4;
    float* op = (float*)&o4;
#pragma unroll
    for (int q = 0; q < 4; q++) op[q] = acc[q] + off_b[ocq * 4 + q];
    *(float4*)&off[((long)((b * 14 + oy) * 14 + ox)) * 32 + ocq * 4] = o4;
}

// ---------------------------------------------------------------------------
// K3: bilinear sampling -> S bf16 [n][k], k = kk*96 + c.
// ---------------------------------------------------------------------------
typedef __attribute__((ext_vector_type(4))) unsigned short ushort4v;

__global__ __launch_bounds__(384) void k3_sample(
    const float* __restrict__ h1, const float* __restrict__ off,
    unsigned short* __restrict__ S)
{
    const int p = blockIdx.x;     // 0..195
    const int b = blockIdx.y;     // 0..63
    const int y = p / 14, xo = p % 14;
    const int tid = threadIdx.x;
    const int c4 = tid % 24, kk = tid / 24;
    const int kh = kk >> 2, kw = kk & 3;

    const float* ob = off + ((long)((b * 14 + y) * 14 + xo)) * 32;
    float dy = ob[kk * 2];
    float dx = ob[kk * 2 + 1];

    float py = (float)(y * 4 + kh) + dy;
    float px = (float)(xo * 4 + kw) + dx;
    float y0f = floorf(py), x0f = floorf(px);
    float wy = py - y0f, wx = px - x0f;
    int y0 = (int)y0f, x0 = (int)x0f;
    int y1 = y0 + 1,  x1 = x0 + 1;

    float my0 = (y0 >= 0 && y0 < 56) ? 1.f : 0.f;
    float my1 = (y1 >= 0 && y1 < 56) ? 1.f : 0.f;
    float mx0 = (x0 >= 0 && x0 < 56) ? 1.f : 0.f;
    float mx1 = (x1 >= 0 && x1 < 56) ? 1.f : 0.f;
    int y0c = min(max(y0, 0), 55), y1c = min(max(y1, 0), 55);
    int x0c = min(max(x0, 0), 55), x1c = min(max(x1, 0), 55);

    const float* hb = h1 + (long)b * 56 * 56 * 96 + c4 * 4;
    float4 v00 = *(const float4*)&hb[(y0c * 56 + x0c) * 96];
    float4 v01 = *(const float4*)&hb[(y0c * 56 + x1c) * 96];
    float4 v10 = *(const float4*)&hb[(y1c * 56 + x0c) * 96];
    float4 v11 = *(const float4*)&hb[(y1c * 56 + x1c) * 96];

    float w00 = my0 * mx0 * (1.f - wy) * (1.f - wx);
    float w01 = my0 * mx1 * (1.f - wy) * wx;
    float w10 = my1 * mx0 * wy * (1.f - wx);
    float w11 = my1 * mx1 * wy * wx;

    ushort4v rr;
    rr.x = f2bf(v00.x * w00 + v01.x * w01 + v10.x * w10 + v11.x * w11);
    rr.y = f2bf(v00.y * w00 + v01.y * w01 + v10.y * w10 + v11.y * w11);
    rr.z = f2bf(v00.z * w00 + v01.z * w01 + v10.z * w10 + v11.z * w11);
    rr.w = f2bf(v00.w * w00 + v01.w * w01 + v10.w * w10 + v11.w * w11);

    long n = (long)b * 196 + p;
    *(ushort4v*)&S[n * 1536 + kk * 96 + c4 * 4] = rr;
}

// ---------------------------------------------------------------------------
// K4: bf16 MFMA GEMM  C[n][oc] = S[n][k] * Wtb[oc][k]^T  (N=12544,M=768,K=1536)
// m97 structure: 128x128 block tile, BK=32, 4 waves (2x2), each wave 4x4
// MFMA tiles of 16x16x32. global_load_lds width=16 staging, row-major
// [row][32k] LDS (contiguous — required by global_load_lds lane ordering).
// Epilogue: leaky(acc + t2[oc]) -> out (already (B,P,C) layout).
// ---------------------------------------------------------------------------
typedef __attribute__((ext_vector_type(8))) short bf16x8;
typedef __attribute__((ext_vector_type(4))) float floatx4;

__global__ __launch_bounds__(256) void k4_gemm_mfma(
    const unsigned short* __restrict__ S,    // [12544][1536] bf16
    const unsigned short* __restrict__ Wtb,  // [768][1536]  bf16 (B^T, scaled)
    const float* __restrict__ t2, float* __restrict__ out)
{
    const int tid  = threadIdx.x;
    const int wave = tid >> 6;
    const int lane = tid & 63;
    const int oc0 = blockIdx.x * 128;
    const int n0  = blockIdx.y * 128;
    const int wr  = wave >> 1, wc = wave & 1;    // wave quadrant (n, oc)
    const int m    = lane & 15;                  // row/col within 16
    const int quad = lane >> 4;                  // k-group

    __shared__ unsigned short sA[128 * 32];      // [n_local][k] 64 B rows
    __shared__ unsigned short sB[128 * 32];      // [oc_local][k]

    // staging: wave w loads rows [w*32, w*32+32); 16 rows / instruction.
    const int srow  = wave * 32 + (lane >> 2);
    const int skoff = (lane & 3) * 8;
    const unsigned short* gA0 = S   + (long)(n0  + srow) * 1536 + skoff;
    const unsigned short* gA1 = gA0 + 16L * 1536;
    const unsigned short* gB0 = Wtb + (long)(oc0 + srow) * 1536 + skoff;
    const unsigned short* gB1 = gB0 + 16L * 1536;
    unsigned short* lA0 = &sA[(wave * 32 +  0) * 32];
    unsigned short* lA1 = &sA[(wave * 32 + 16) * 32];
    unsigned short* lB0 = &sB[(wave * 32 +  0) * 32];
    unsigned short* lB1 = &sB[(wave * 32 + 16) * 32];

    floatx4 acc[4][4];
#pragma unroll
    for (int i = 0; i < 4; i++)
#pragma unroll
        for (int j = 0; j < 4; j++) acc[i][j] = (floatx4)0.f;

    for (int kt = 0; kt < 48; ++kt) {
        __syncthreads();   // previous iter's LDS reads done before overwrite
        __builtin_amdgcn_global_load_lds(
            (const __attribute__((address_space(1))) void*)gA0,
            (__attribute__((address_space(3))) void*)lA0, 16, 0, 0);
        __builtin_amdgcn_global_load_lds(
            (const __attribute__((address_space(1))) void*)gA1,
            (__attribute__((address_space(3))) void*)lA1, 16, 0, 0);
        __builtin_amdgcn_global_load_lds(
            (const __attribute__((address_space(1))) void*)gB0,
            (__attribute__((address_space(3))) void*)lB0, 16, 0, 0);
        __builtin_amdgcn_global_load_lds(
            (const __attribute__((address_space(1))) void*)gB1,
            (__attribute__((address_space(3))) void*)lB1, 16, 0, 0);
        gA0 += 32; gA1 += 32; gB0 += 32; gB1 += 32;
        __syncthreads();   // staging visible (compiler drains vmcnt at barrier)

        bf16x8 af[4], bf[4];
#pragma unroll
        for (int i = 0; i < 4; i++)
            af[i] = *(const bf16x8*)&sA[(wr * 64 + i * 16 + m) * 32 + quad * 8];
#pragma unroll
        for (int j = 0; j < 4; j++)
            bf[j] = *(const bf16x8*)&sB[(wc * 64 + j * 16 + m) * 32 + quad * 8];
#pragma unroll
        for (int i = 0; i < 4; i++)
#pragma unroll
            for (int j = 0; j < 4; j++)
                acc[i][j] = __builtin_amdgcn_mfma_f32_16x16x32_bf16(
                    af[i], bf[j], acc[i][j], 0, 0, 0);
    }

    // epilogue: C/D layout col(oc)=lane&15, row(n)=quad*4+reg  [m89/m91]
    float tb[4];
#pragma unroll
    for (int j = 0; j < 4; j++) tb[j] = t2[oc0 + wc * 64 + j * 16 + m];
#pragma unroll
    for (int i = 0; i < 4; i++) {
#pragma unroll
        for (int r = 0; r < 4; r++) {
            long n = n0 + wr * 64 + i * 16 + quad * 4 + r;
            float* orow = out + n * 768 + oc0 + wc * 64 + m;
#pragma unroll
            for (int j = 0; j < 4; j++) {
                float v = acc[i][j][r] + tb[j];
                orow[j * 16] = v >= 0.f ? v : SLOPE * v;
            }
        }
    }
}

// ---------------------------------------------------------------------------
extern "C" void kernel_launch(void* const* d_in, const int* in_sizes, int n_in,
                              void* d_out, int out_size, void* d_ws, size_t ws_size,
                              hipStream_t stream)
{
    const float* x      = (const float*)d_in[0];
    const float* stem_w = (const float*)d_in[1];
    const float* stem_b = (const float*)d_in[2];
    const float* bn1_g  = (const float*)d_in[3];
    const float* bn1_b  = (const float*)d_in[4];
    const float* bn1_m  = (const float*)d_in[5];
    const float* bn1_v  = (const float*)d_in[6];
    const float* off_w  = (const float*)d_in[7];
    const float* off_b  = (const float*)d_in[8];
    const float* dcn_w  = (const float*)d_in[9];
    const float* dcn_b  = (const float*)d_in[10];
    const float* bn2_g  = (const float*)d_in[11];
    const float* bn2_b  = (const float*)d_in[12];
    const float* bn2_m  = (const float*)d_in[13];
    const float* bn2_v  = (const float*)d_in[14];

    float* ws  = (float*)d_ws;        // needs 119.8 MB
    float* out = (float*)d_out;

    float* h1  = ws + WS_H1;
    float* off = ws + WS_OFF;
    float* wt4 = ws + WS_WT4;
    float* w1t = ws + WS_W1T;
    float* s1  = ws + WS_S1;
    float* t1  = ws + WS_T1;
    float* t2  = ws + WS_T2;
    unsigned short* Sb  = (unsigned short*)(ws + WS_SB);
    unsigned short* Wtb = (unsigned short*)(ws + WS_WTB);

    k0_prep<<<4823, 256, 0, stream>>>(stem_w, stem_b, bn1_g, bn1_b, bn1_m, bn1_v,
                                      off_w, dcn_w, dcn_b, bn2_g, bn2_b, bn2_m,
                                      bn2_v, ws);
    k1_stem<<<dim3(56, 64), 256, 0, stream>>>(x, w1t, s1, t1, h1);
    k2_off<<<392, 256, 0, stream>>>(h1, wt4, off_b, off);
    k3_sample<<<dim3(196, 64), 384, 0, stream>>>(h1, off, Sb);
    k4_gemm_mfma<<<dim3(6, 98), 256, 0, stream>>>(Sb, Wtb, t2, out);
}

// Round 3
// 262.424 us; speedup vs baseline: 3.1176x; 1.6015x over previous
//
#include <hip/hip_runtime.h>

#define EPS   1e-5f
#define SLOPE 0.01f

// ---------------------------------------------------------------------------
// Workspace layout (float offsets). Total 39,556,544 floats = 158.2 MB.
// ---------------------------------------------------------------------------
#define WS_H1   0L            // h1   NHWC f32 (64,56,56,96)    19267584
#define WS_OFF  19267584L     // off  NHWC f32 (64,14,14,32)      401408
#define WS_W1T  19668992L     // w1t  f32 [k=48][c=96]              4608
#define WS_S1   19673600L     // bn1 scale f32 [96]
#define WS_T1   19673696L     // bn1 bias  f32 [96]
#define WS_T2   19673792L     // fused dcn_b+bn2 bias f32 [768]
#define WS_SB   19674560L     // S    bf16 [n=12544][k=1536]   (9633792 f)
#define WS_H1P  29308352L     // h1p  bf16 [n=12544][k=1536]   (9633792 f)
#define WS_WTB  38942144L     // Wtb  bf16 [oc=768][k=1536]    (589824 f)
#define WS_WOB  39531968L     // Wob  bf16 [oc=32][k=1536]     (24576 f)

__device__ __forceinline__ unsigned short f2bf(float f) {
    unsigned int u = __builtin_bit_cast(unsigned int, f);
    u += 0x7fffu + ((u >> 16) & 1u);
    return (unsigned short)(u >> 16);
}

typedef __attribute__((ext_vector_type(4))) unsigned short ushort4v;
typedef __attribute__((ext_vector_type(8))) short bf16x8;
typedef __attribute__((ext_vector_type(4))) float floatx4;

// ---------------------------------------------------------------------------
// K0: weight prep.
//   Wtb[oc][k] = bf16( dcn_w[oc][c][kk] * inv2[oc] ),  k = kk*96 + c  (B^T)
//   Wob[oc][k] = bf16( off_w[oc][c][khw] ),            k = khw*96 + c (B^T)
//   w1t[k][c]  = stem_w[c][k]                          (k = ci*16+kh*4+kw)
// ---------------------------------------------------------------------------
__global__ __launch_bounds__(256) void k0_prep(
    const float* __restrict__ stem_w, const float* __restrict__ stem_b,
    const float* __restrict__ bn1_g,  const float* __restrict__ bn1_b,
    const float* __restrict__ bn1_m,  const float* __restrict__ bn1_v,
    const float* __restrict__ off_w,  const float* __restrict__ dcn_w,
    const float* __restrict__ dcn_b,  const float* __restrict__ bn2_g,
    const float* __restrict__ bn2_b,  const float* __restrict__ bn2_m,
    const float* __restrict__ bn2_v,  float* __restrict__ ws)
{
    long i = (long)blockIdx.x * 256 + threadIdx.x;
    unsigned short* Wtb = (unsigned short*)(ws + WS_WTB);
    unsigned short* Wob = (unsigned short*)(ws + WS_WOB);
    if (i < 1179648L) {                       // Wtb (bf16, [oc][k])
        int oc = (int)(i / 1536), k = (int)(i % 1536);
        int kk = k / 96, c = k % 96;
        float inv2 = bn2_g[oc] * rsqrtf(bn2_v[oc] + EPS);
        Wtb[i] = f2bf(dcn_w[oc * 1536 + c * 16 + kk] * inv2);
    } else if (i < 1228800L) {                // Wob (bf16, [oc][k])
        int i2 = (int)(i - 1179648L);
        int oc = i2 / 1536, k = i2 % 1536;
        int khw = k / 96, c = k % 96;
        Wob[i2] = f2bf(off_w[oc * 1536 + c * 16 + khw]);
    } else if (i < 1233408L) {                // w1t
        int i3 = (int)(i - 1228800L);
        int k = i3 / 96, c = i3 % 96;
        ws[WS_W1T + i3] = stem_w[c * 48 + k];
    } else if (i < 1233504L) {                // s1
        int c = (int)(i - 1233408L);
        ws[WS_S1 + c] = bn1_g[c] * rsqrtf(bn1_v[c] + EPS);
    } else if (i < 1233600L) {                // t1
        int c = (int)(i - 1233504L);
        float s = bn1_g[c] * rsqrtf(bn1_v[c] + EPS);
        ws[WS_T1 + c] = stem_b[c] * s + bn1_b[c] - bn1_m[c] * s;
    } else if (i < 1234368L) {                // t2
        int oc = (int)(i - 1233600L);
        float inv2 = bn2_g[oc] * rsqrtf(bn2_v[oc] + EPS);
        ws[WS_T2 + oc] = dcn_b[oc] * inv2 + bn2_b[oc] - bn2_m[oc] * inv2;
    }
}

// ---------------------------------------------------------------------------
// K1: stem conv (stride 4 == kernel 4, non-overlapping) + bn1 + leaky.
// Emits h1 NHWC f32 (for sampling) AND h1p patch-major bf16 [n][k]
// (k = (kh*4+kw)*96 + c) — the exact im2col the offset conv needs, which is
// a pure permutation of h1 because stride == kernel.
// ---------------------------------------------------------------------------
__global__ __launch_bounds__(256) void k1_stem(
    const float* __restrict__ x, const float* __restrict__ w1t,
    const float* __restrict__ s1, const float* __restrict__ t1,
    float* __restrict__ h1, unsigned short* __restrict__ h1p)
{
    const int oy = blockIdx.x;   // 0..55
    const int b  = blockIdx.y;   // 0..63
    const int tid = threadIdx.x;

    __shared__ float xs[3 * 4 * 224];   // [ci][kh][xx]
    __shared__ float wsh[48 * 100];     // [k][c], pad stride 100
    __shared__ float s1s[96], t1s[96];

    for (int i = tid; i < 2688; i += 256) {
        int ci = i / 896, r = i % 896;
        int kh = r / 224, xx = r % 224;
        xs[i] = x[((long)(b * 3 + ci) * 224 + oy * 4 + kh) * 224 + xx];
    }
    for (int i = tid; i < 4608; i += 256) {
        int k = i / 96, c = i % 96;
        wsh[k * 100 + c] = w1t[i];
    }
    if (tid < 96) { s1s[tid] = s1[tid]; t1s[tid] = t1[tid]; }
    __syncthreads();

    for (int u = tid; u < 336; u += 256) {   // 14 oxg * 24 cg
        int oxg = u / 24, cg = u % 24;
        float acc[4][4] = {};
#pragma unroll
        for (int ci = 0; ci < 3; ci++) {
#pragma unroll
            for (int kh = 0; kh < 4; kh++) {
                const float* xrow = &xs[(ci * 4 + kh) * 224 + oxg * 16];
                float4 xv[4], wv[4];
#pragma unroll
                for (int o = 0; o < 4; o++) xv[o] = *(const float4*)&xrow[o * 4];
#pragma unroll
                for (int kw = 0; kw < 4; kw++)
                    wv[kw] = *(const float4*)&wsh[(ci * 16 + kh * 4 + kw) * 100 + cg * 4];
#pragma unroll
                for (int kw = 0; kw < 4; kw++) {
                    const float* wf = (const float*)&wv[kw];
#pragma unroll
                    for (int o = 0; o < 4; o++) {
                        float xv_s = ((const float*)&xv[o])[kw];
#pragma unroll
                        for (int cc = 0; cc < 4; cc++)
                            acc[o][cc] += xv_s * wf[cc];
                    }
                }
            }
        }
#pragma unroll
        for (int o = 0; o < 4; o++) {
            float4 r;
            float* rp = (float*)&r;
#pragma unroll
            for (int cc = 0; cc < 4; cc++) {
                int c = cg * 4 + cc;
                float v = acc[o][cc] * s1s[c] + t1s[c];
                rp[cc] = v >= 0.f ? v : SLOPE * v;
            }
            *(float4*)&h1[((long)((b * 56 + oy) * 56) + oxg * 4 + o) * 96 + cg * 4] = r;
            // patch-major bf16 copy: x = oxg*4+o -> (ox2=oxg, kw2=o); oy -> (oy2=oy>>2, kh2=oy&3)
            ushort4v hp;
            hp.x = f2bf(rp[0]); hp.y = f2bf(rp[1]);
            hp.z = f2bf(rp[2]); hp.w = f2bf(rp[3]);
            long np = ((long)(b * 196 + (oy >> 2) * 14 + oxg) * 16 + (oy & 3) * 4 + o);
            *(ushort4v*)&h1p[np * 96 + cg * 4] = hp;
        }
    }
}

// ---------------------------------------------------------------------------
// K2: offset conv as bf16 MFMA GEMM: off[n][oc] = h1p[n][k] * Wob[oc][k]^T
// N=12544, M=32, K=1536. 128x32 block tile, BK=32, 4 waves (each wave owns
// 32 n-rows x 32 oc = 2x2 MFMA 16x16x32 tiles). 98 blocks.
// ---------------------------------------------------------------------------
__global__ __launch_bounds__(256) void k2_mfma(
    const unsigned short* __restrict__ A,    // h1p [12544][1536] bf16
    const unsigned short* __restrict__ Wob,  // [32][1536] bf16
    const float* __restrict__ off_b, float* __restrict__ off)
{
    const int tid  = threadIdx.x;
    const int wave = tid >> 6;
    const int lane = tid & 63;
    const int n0   = blockIdx.x * 128;
    const int m    = lane & 15;
    const int quad = lane >> 4;

    __shared__ unsigned short sA[128 * 32];  // [n_local][k] 64 B rows
    __shared__ unsigned short sB[32 * 32];   // [oc][k]

    const int srow  = wave * 32 + (lane >> 2);
    const int skoff = (lane & 3) * 8;
    const unsigned short* gA0 = A + (long)(n0 + srow) * 1536 + skoff;
    const unsigned short* gA1 = gA0 + 16L * 1536;
    unsigned short* lA0 = &sA[(wave * 32 +  0) * 32];
    unsigned short* lA1 = &sA[(wave * 32 + 16) * 32];
    // B: waves 0,1 stage 16 oc-rows each
    const unsigned short* gB = Wob + (long)((wave & 1) * 16 + (lane >> 2)) * 1536 + skoff;
    unsigned short* lB = &sB[((wave & 1) * 16) * 32];

    floatx4 acc[2][2];
#pragma unroll
    for (int i = 0; i < 2; i++)
#pragma unroll
        for (int j = 0; j < 2; j++) acc[i][j] = (floatx4)0.f;

    for (int kt = 0; kt < 48; ++kt) {
        __syncthreads();
        __builtin_amdgcn_global_load_lds(
            (const __attribute__((address_space(1))) void*)gA0,
            (__attribute__((address_space(3))) void*)lA0, 16, 0, 0);
        __builtin_amdgcn_global_load_lds(
            (const __attribute__((address_space(1))) void*)gA1,
            (__attribute__((address_space(3))) void*)lA1, 16, 0, 0);
        if (wave < 2)
            __builtin_amdgcn_global_load_lds(
                (const __attribute__((address_space(1))) void*)gB,
                (__attribute__((address_space(3))) void*)lB, 16, 0, 0);
        gA0 += 32; gA1 += 32; gB += 32;
        __syncthreads();

        bf16x8 af[2], bfr[2];
#pragma unroll
        for (int i = 0; i < 2; i++)
            af[i] = *(const bf16x8*)&sA[(wave * 32 + i * 16 + m) * 32 + quad * 8];
#pragma unroll
        for (int j = 0; j < 2; j++)
            bfr[j] = *(const bf16x8*)&sB[(j * 16 + m) * 32 + quad * 8];
#pragma unroll
        for (int i = 0; i < 2; i++)
#pragma unroll
            for (int j = 0; j < 2; j++)
                acc[i][j] = __builtin_amdgcn_mfma_f32_16x16x32_bf16(
                    af[i], bfr[j], acc[i][j], 0, 0, 0);
    }

    // epilogue: col(oc)=lane&15, row(n)=quad*4+reg ; add off_b
    float tb[2];
#pragma unroll
    for (int j = 0; j < 2; j++) tb[j] = off_b[j * 16 + m];
#pragma unroll
    for (int i = 0; i < 2; i++)
#pragma unroll
        for (int r = 0; r < 4; r++) {
            long n = n0 + wave * 32 + i * 16 + quad * 4 + r;
#pragma unroll
            for (int j = 0; j < 2; j++)
                off[n * 32 + j * 16 + m] = acc[i][j][r] + tb[j];
        }
}

// ---------------------------------------------------------------------------
// K3: bilinear sampling -> S bf16 [n][k], k = kk*96 + c.
// ---------------------------------------------------------------------------
__global__ __launch_bounds__(384) void k3_sample(
    const float* __restrict__ h1, const float* __restrict__ off,
    unsigned short* __restrict__ S)
{
    const int p = blockIdx.x;     // 0..195
    const int b = blockIdx.y;     // 0..63
    const int y = p / 14, xo = p % 14;
    const int tid = threadIdx.x;
    const int c4 = tid % 24, kk = tid / 24;
    const int kh = kk >> 2, kw = kk & 3;

    const float* ob = off + ((long)((b * 14 + y) * 14 + xo)) * 32;
    float dy = ob[kk * 2];
    float dx = ob[kk * 2 + 1];

    float py = (float)(y * 4 + kh) + dy;
    float px = (float)(xo * 4 + kw) + dx;
    float y0f = floorf(py), x0f = floorf(px);
    float wy = py - y0f, wx = px - x0f;
    int y0 = (int)y0f, x0 = (int)x0f;
    int y1 = y0 + 1,  x1 = x0 + 1;

    float my0 = (y0 >= 0 && y0 < 56) ? 1.f : 0.f;
    float my1 = (y1 >= 0 && y1 < 56) ? 1.f : 0.f;
    float mx0 = (x0 >= 0 && x0 < 56) ? 1.f : 0.f;
    float mx1 = (x1 >= 0 && x1 < 56) ? 1.f : 0.f;
    int y0c = min(max(y0, 0), 55), y1c = min(max(y1, 0), 55);
    int x0c = min(max(x0, 0), 55), x1c = min(max(x1, 0), 55);

    const float* hb = h1 + (long)b * 56 * 56 * 96 + c4 * 4;
    float4 v00 = *(const float4*)&hb[(y0c * 56 + x0c) * 96];
    float4 v01 = *(const float4*)&hb[(y0c * 56 + x1c) * 96];
    float4 v10 = *(const float4*)&hb[(y1c * 56 + x0c) * 96];
    float4 v11 = *(const float4*)&hb[(y1c * 56 + x1c) * 96];

    float w00 = my0 * mx0 * (1.f - wy) * (1.f - wx);
    float w01 = my0 * mx1 * (1.f - wy) * wx;
    float w10 = my1 * mx0 * wy * (1.f - wx);
    float w11 = my1 * mx1 * wy * wx;

    ushort4v rr;
    rr.x = f2bf(v00.x * w00 + v01.x * w01 + v10.x * w10 + v11.x * w11);
    rr.y = f2bf(v00.y * w00 + v01.y * w01 + v10.y * w10 + v11.y * w11);
    rr.z = f2bf(v00.z * w00 + v01.z * w01 + v10.z * w10 + v11.z * w11);
    rr.w = f2bf(v00.w * w00 + v01.w * w01 + v10.w * w10 + v11.w * w11);

    long n = (long)b * 196 + p;
    *(ushort4v*)&S[n * 1536 + kk * 96 + c4 * 4] = rr;
}

// ---------------------------------------------------------------------------
// K4: bf16 MFMA GEMM  C[n][oc] = S[n][k] * Wtb[oc][k]^T  (N=12544,M=768,K=1536)
// 128x128 tile, BK=32, 4 waves (2x2), each wave 4x4 MFMA 16x16x32 tiles.
// Epilogue: leaky(acc + t2[oc]) -> out (already (B,P,C) layout).
// ---------------------------------------------------------------------------
__global__ __launch_bounds__(256) void k4_gemm_mfma(
    const unsigned short* __restrict__ S,    // [12544][1536] bf16
    const unsigned short* __restrict__ Wtb,  // [768][1536]  bf16 (B^T, scaled)
    const float* __restrict__ t2, float* __restrict__ out)
{
    const int tid  = threadIdx.x;
    const int wave = tid >> 6;
    const int lane = tid & 63;
    const int oc0 = blockIdx.x * 128;
    const int n0  = blockIdx.y * 128;
    const int wr  = wave >> 1, wc = wave & 1;
    const int m    = lane & 15;
    const int quad = lane >> 4;

    __shared__ unsigned short sA[128 * 32];
    __shared__ unsigned short sB[128 * 32];

    const int srow  = wave * 32 + (lane >> 2);
    const int skoff = (lane & 3) * 8;
    const unsigned short* gA0 = S   + (long)(n0  + srow) * 1536 + skoff;
    const unsigned short* gA1 = gA0 + 16L * 1536;
    const unsigned short* gB0 = Wtb + (long)(oc0 + srow) * 1536 + skoff;
    const unsigned short* gB1 = gB0 + 16L * 1536;
    unsigned short* lA0 = &sA[(wave * 32 +  0) * 32];
    unsigned short* lA1 = &sA[(wave * 32 + 16) * 32];
    unsigned short* lB0 = &sB[(wave * 32 +  0) * 32];
    unsigned short* lB1 = &sB[(wave * 32 + 16) * 32];

    floatx4 acc[4][4];
#pragma unroll
    for (int i = 0; i < 4; i++)
#pragma unroll
        for (int j = 0; j < 4; j++) acc[i][j] = (floatx4)0.f;

    for (int kt = 0; kt < 48; ++kt) {
        __syncthreads();
        __builtin_amdgcn_global_load_lds(
            (const __attribute__((address_space(1))) void*)gA0,
            (__attribute__((address_space(3))) void*)lA0, 16, 0, 0);
        __builtin_amdgcn_global_load_lds(
            (const __attribute__((address_space(1))) void*)gA1,
            (__attribute__((address_space(3))) void*)lA1, 16, 0, 0);
        __builtin_amdgcn_global_load_lds(
            (const __attribute__((address_space(1))) void*)gB0,
            (__attribute__((address_space(3))) void*)lB0, 16, 0, 0);
        __builtin_amdgcn_global_load_lds(
            (const __attribute__((address_space(1))) void*)gB1,
            (__attribute__((address_space(3))) void*)lB1, 16, 0, 0);
        gA0 += 32; gA1 += 32; gB0 += 32; gB1 += 32;
        __syncthreads();

        bf16x8 af[4], bf[4];
#pragma unroll
        for (int i = 0; i < 4; i++)
            af[i] = *(const bf16x8*)&sA[(wr * 64 + i * 16 + m) * 32 + quad * 8];
#pragma unroll
        for (int j = 0; j < 4; j++)
            bf[j] = *(const bf16x8*)&sB[(wc * 64 + j * 16 + m) * 32 + quad * 8];
#pragma unroll
        for (int i = 0; i < 4; i++)
#pragma unroll
            for (int j = 0; j < 4; j++)
                acc[i][j] = __builtin_amdgcn_mfma_f32_16x16x32_bf16(
                    af[i], bf[j], acc[i][j], 0, 0, 0);
    }

    float tb[4];
#pragma unroll
    for (int j = 0; j < 4; j++) tb[j] = t2[oc0 + wc * 64 + j * 16 + m];
#pragma unroll
    for (int i = 0; i < 4; i++) {
#pragma unroll
        for (int r = 0; r < 4; r++) {
            long n = n0 + wr * 64 + i * 16 + quad * 4 + r;
            float* orow = out + n * 768 + oc0 + wc * 64 + m;
#pragma unroll
            for (int j = 0; j < 4; j++) {
                float v = acc[i][j][r] + tb[j];
                orow[j * 16] = v >= 0.f ? v : SLOPE * v;
            }
        }
    }
}

// ---------------------------------------------------------------------------
extern "C" void kernel_launch(void* const* d_in, const int* in_sizes, int n_in,
                              void* d_out, int out_size, void* d_ws, size_t ws_size,
                              hipStream_t stream)
{
    const float* x      = (const float*)d_in[0];
    const float* stem_w = (const float*)d_in[1];
    const float* stem_b = (const float*)d_in[2];
    const float* bn1_g  = (const float*)d_in[3];
    const float* bn1_b  = (const float*)d_in[4];
    const float* bn1_m  = (const float*)d_in[5];
    const float* bn1_v  = (const float*)d_in[6];
    const float* off_w  = (const float*)d_in[7];
    const float* off_b  = (const float*)d_in[8];
    const float* dcn_w  = (const float*)d_in[9];
    const float* dcn_b  = (const float*)d_in[10];
    const float* bn2_g  = (const float*)d_in[11];
    const float* bn2_b  = (const float*)d_in[12];
    const float* bn2_m  = (const float*)d_in[13];
    const float* bn2_v  = (const float*)d_in[14];

    float* ws  = (float*)d_ws;        // needs 158.3 MB
    float* out = (float*)d_out;

    float* h1  = ws + WS_H1;
    float* off = ws + WS_OFF;
    float* w1t = ws + WS_W1T;
    float* s1  = ws + WS_S1;
    float* t1  = ws + WS_T1;
    float* t2  = ws + WS_T2;
    unsigned short* Sb  = (unsigned short*)(ws + WS_SB);
    unsigned short* h1p = (unsigned short*)(ws + WS_H1P);
    unsigned short* Wtb = (unsigned short*)(ws + WS_WTB);
    unsigned short* Wob = (unsigned short*)(ws + WS_WOB);

    k0_prep<<<4823, 256, 0, stream>>>(stem_w, stem_b, bn1_g, bn1_b, bn1_m, bn1_v,
                                      off_w, dcn_w, dcn_b, bn2_g, bn2_b, bn2_m,
                                      bn2_v, ws);
    k1_stem<<<dim3(56, 64), 256, 0, stream>>>(x, w1t, s1, t1, h1, h1p);
    k2_mfma<<<98, 256, 0, stream>>>(h1p, Wob, off_b, off);
    k3_sample<<<dim3(196, 64), 384, 0, stream>>>(h1, off, Sb);
    k4_gemm_mfma<<<dim3(6, 98), 256, 0, stream>>>(Sb, Wtb, t2, out);
}

// Round 4
// 252.653 us; speedup vs baseline: 3.2381x; 1.0387x over previous
//
#include <hip/hip_runtime.h>

#define EPS   1e-5f
#define SLOPE 0.01f

// ---------------------------------------------------------------------------
// Workspace layout (float offsets). Total 20,288,960 floats = 81.2 MB.
// ---------------------------------------------------------------------------
#define WS_H1B  0L            // h1  bf16 NHWC (64,56,56,96)   (9633792 f)
#define WS_OFF  9633792L      // off f32 [n=12544][32]            401408
#define WS_W1T  10035200L     // w1t f32 [k=48][c=96]               4608
#define WS_S1   10039808L     // bn1 scale f32 [96]
#define WS_T1   10039904L     // bn1 bias  f32 [96]
#define WS_T2   10040000L     // fused dcn_b+bn2 bias f32 [768]
#define WS_SB   10040768L     // S   bf16 [n=12544][k=1536]    (9633792 f)
#define WS_WTB  19674560L     // Wtb bf16 [oc=768][k=1536]      (589824 f)
#define WS_WOB  20264384L     // Wob bf16 [oc=32][k=1536]        (24576 f)

__device__ __forceinline__ unsigned short f2bf(float f) {
    unsigned int u = __builtin_bit_cast(unsigned int, f);
    u += 0x7fffu + ((u >> 16) & 1u);
    return (unsigned short)(u >> 16);
}
__device__ __forceinline__ float bf2f(unsigned short u) {
    unsigned int t = ((unsigned int)u) << 16;
    return __builtin_bit_cast(float, t);
}

typedef __attribute__((ext_vector_type(4))) unsigned short ushort4v;
typedef __attribute__((ext_vector_type(8))) short bf16x8;
typedef __attribute__((ext_vector_type(4))) float floatx4;

// ---------------------------------------------------------------------------
// K0: weight prep.
//   Wtb[oc][k] = bf16( dcn_w[oc][c][kk] * inv2[oc] ),  k = kk*96 + c  (B^T)
//   Wob[oc][k] = bf16( off_w[oc][c][khw] ),            k = khw*96 + c (B^T)
//   w1t[k][c]  = stem_w[c][k]                          (k = ci*16+kh*4+kw)
// ---------------------------------------------------------------------------
__global__ __launch_bounds__(256) void k0_prep(
    const float* __restrict__ stem_w, const float* __restrict__ stem_b,
    const float* __restrict__ bn1_g,  const float* __restrict__ bn1_b,
    const float* __restrict__ bn1_m,  const float* __restrict__ bn1_v,
    const float* __restrict__ off_w,  const float* __restrict__ dcn_w,
    const float* __restrict__ dcn_b,  const float* __restrict__ bn2_g,
    const float* __restrict__ bn2_b,  const float* __restrict__ bn2_m,
    const float* __restrict__ bn2_v,  float* __restrict__ ws)
{
    long i = (long)blockIdx.x * 256 + threadIdx.x;
    unsigned short* Wtb = (unsigned short*)(ws + WS_WTB);
    unsigned short* Wob = (unsigned short*)(ws + WS_WOB);
    if (i < 1179648L) {                       // Wtb (bf16, [oc][k])
        int oc = (int)(i / 1536), k = (int)(i % 1536);
        int kk = k / 96, c = k % 96;
        float inv2 = bn2_g[oc] * rsqrtf(bn2_v[oc] + EPS);
        Wtb[i] = f2bf(dcn_w[oc * 1536 + c * 16 + kk] * inv2);
    } else if (i < 1228800L) {                // Wob (bf16, [oc][k])
        int i2 = (int)(i - 1179648L);
        int oc = i2 / 1536, k = i2 % 1536;
        int khw = k / 96, c = k % 96;
        Wob[i2] = f2bf(off_w[oc * 1536 + c * 16 + khw]);
    } else if (i < 1233408L) {                // w1t
        int i3 = (int)(i - 1228800L);
        int k = i3 / 96, c = i3 % 96;
        ws[WS_W1T + i3] = stem_w[c * 48 + k];
    } else if (i < 1233504L) {                // s1
        int c = (int)(i - 1233408L);
        ws[WS_S1 + c] = bn1_g[c] * rsqrtf(bn1_v[c] + EPS);
    } else if (i < 1233600L) {                // t1
        int c = (int)(i - 1233504L);
        float s = bn1_g[c] * rsqrtf(bn1_v[c] + EPS);
        ws[WS_T1 + c] = stem_b[c] * s + bn1_b[c] - bn1_m[c] * s;
    } else if (i < 1234368L) {                // t2
        int oc = (int)(i - 1233600L);
        float inv2 = bn2_g[oc] * rsqrtf(bn2_v[oc] + EPS);
        ws[WS_T2 + oc] = dcn_b[oc] * inv2 + bn2_b[oc] - bn2_m[oc] * inv2;
    }
}

// ---------------------------------------------------------------------------
// K1: stem conv (stride 4 == kernel 4) + bn1 + leaky -> h1 bf16 NHWC only.
// 384 threads: 336 work-units (14 oxg x 24 cg) in a single pass (no 2x tail).
// ---------------------------------------------------------------------------
__global__ __launch_bounds__(384) void k1_stem(
    const float* __restrict__ x, const float* __restrict__ w1t,
    const float* __restrict__ s1, const float* __restrict__ t1,
    unsigned short* __restrict__ h1)
{
    const int oy = blockIdx.x;   // 0..55
    const int b  = blockIdx.y;   // 0..63
    const int tid = threadIdx.x;

    __shared__ float xs[3 * 4 * 224];   // [ci][kh][xx]
    __shared__ float wsh[48 * 100];     // [k][c], pad stride 100
    __shared__ float s1s[96], t1s[96];

    for (int i = tid; i < 2688; i += 384) {
        int ci = i / 896, r = i % 896;
        int kh = r / 224, xx = r % 224;
        xs[i] = x[((long)(b * 3 + ci) * 224 + oy * 4 + kh) * 224 + xx];
    }
    for (int i = tid; i < 4608; i += 384) {
        int k = i / 96, c = i % 96;
        wsh[k * 100 + c] = w1t[i];
    }
    if (tid < 96) { s1s[tid] = s1[tid]; t1s[tid] = t1[tid]; }
    __syncthreads();

    if (tid < 336) {
        int oxg = tid / 24, cg = tid % 24;
        float acc[4][4] = {};
#pragma unroll
        for (int ci = 0; ci < 3; ci++) {
#pragma unroll
            for (int kh = 0; kh < 4; kh++) {
                const float* xrow = &xs[(ci * 4 + kh) * 224 + oxg * 16];
                float4 xv[4], wv[4];
#pragma unroll
                for (int o = 0; o < 4; o++) xv[o] = *(const float4*)&xrow[o * 4];
#pragma unroll
                for (int kw = 0; kw < 4; kw++)
                    wv[kw] = *(const float4*)&wsh[(ci * 16 + kh * 4 + kw) * 100 + cg * 4];
#pragma unroll
                for (int kw = 0; kw < 4; kw++) {
                    const float* wf = (const float*)&wv[kw];
#pragma unroll
                    for (int o = 0; o < 4; o++) {
                        float xv_s = ((const float*)&xv[o])[kw];
#pragma unroll
                        for (int cc = 0; cc < 4; cc++)
                            acc[o][cc] += xv_s * wf[cc];
                    }
                }
            }
        }
#pragma unroll
        for (int o = 0; o < 4; o++) {
            ushort4v hp;
#pragma unroll
            for (int cc = 0; cc < 4; cc++) {
                int c = cg * 4 + cc;
                float v = acc[o][cc] * s1s[c] + t1s[c];
                v = v >= 0.f ? v : SLOPE * v;
                ((unsigned short*)&hp)[cc] = f2bf(v);
            }
            *(ushort4v*)&h1[((long)((b * 56 + oy) * 56) + oxg * 4 + o) * 96 + cg * 4] = hp;
        }
    }
}

// ---------------------------------------------------------------------------
// K2: offset conv as bf16 MFMA GEMM reading im2col rows DIRECTLY from h1
// (stride==kernel => im2col is an address permutation; each BK=32 chunk
// k = khw*96 + [c0,c0+32) is 32 contiguous channels at one pixel).
// off[n][oc] = im2col(h1)[n][k] * Wob[oc][k]^T.  N=12544, M=32, K=1536.
// 128x32 tile, 4 waves, each wave 2x2 MFMA 16x16x32 tiles. 98 blocks.
// ---------------------------------------------------------------------------
__global__ __launch_bounds__(256) void k2_mfma(
    const unsigned short* __restrict__ h1,   // bf16 NHWC
    const unsigned short* __restrict__ Wob,  // [32][1536] bf16
    const float* __restrict__ off_b, float* __restrict__ off)
{
    const int tid  = threadIdx.x;
    const int wave = tid >> 6;
    const int lane = tid & 63;
    const int n0   = blockIdx.x * 128;
    const int m    = lane & 15;
    const int quad = lane >> 4;

    __shared__ unsigned short sA[128 * 32];  // [n_local][k-chunk] 64 B rows
    __shared__ unsigned short sB[32 * 32];   // [oc][k-chunk]

    const int skoff = (lane & 3) * 8;
    // rows n_a = n0+wave*32+(lane>>2), n_b = n_a+16 -> pixel base indices
    int n_a = n0 + wave * 32 + (lane >> 2);
    int n_b = n_a + 16;
    int ba = n_a / 196, pa = n_a % 196;
    int bb = n_b / 196, pb = n_b % 196;
    long pixa = ((long)(ba * 56 + (pa / 14) * 4) * 56 + (pa % 14) * 4);
    long pixb = ((long)(bb * 56 + (pb / 14) * 4) * 56 + (pb % 14) * 4);

    const unsigned short* gB = Wob + (long)((wave & 1) * 16 + (lane >> 2)) * 1536 + skoff;
    unsigned short* lA0 = &sA[(wave * 32 +  0) * 32];
    unsigned short* lA1 = &sA[(wave * 32 + 16) * 32];
    unsigned short* lB  = &sB[((wave & 1) * 16) * 32];

    floatx4 acc[2][2];
#pragma unroll
    for (int i = 0; i < 2; i++)
#pragma unroll
        for (int j = 0; j < 2; j++) acc[i][j] = (floatx4)0.f;

    for (int kt = 0; kt < 48; ++kt) {
        int khw = kt / 3;                      // kernel tap 0..15
        int c0  = (kt - khw * 3) * 32;         // channel chunk 0/32/64
        int kh  = khw >> 2, kw = khw & 3;
        long eoff = (long)(kh * 56 + kw) * 96 + c0 + skoff;
        const unsigned short* gA0 = h1 + pixa * 96 + eoff;
        const unsigned short* gA1 = h1 + pixb * 96 + eoff;

        __syncthreads();
        __builtin_amdgcn_global_load_lds(
            (const __attribute__((address_space(1))) void*)gA0,
            (__attribute__((address_space(3))) void*)lA0, 16, 0, 0);
        __builtin_amdgcn_global_load_lds(
            (const __attribute__((address_space(1))) void*)gA1,
            (__attribute__((address_space(3))) void*)lA1, 16, 0, 0);
        if (wave < 2)
            __builtin_amdgcn_global_load_lds(
                (const __attribute__((address_space(1))) void*)gB,
                (__attribute__((address_space(3))) void*)lB, 16, 0, 0);
        gB += 32;
        __syncthreads();

        bf16x8 af[2], bfr[2];
#pragma unroll
        for (int i = 0; i < 2; i++)
            af[i] = *(const bf16x8*)&sA[(wave * 32 + i * 16 + m) * 32 + quad * 8];
#pragma unroll
        for (int j = 0; j < 2; j++)
            bfr[j] = *(const bf16x8*)&sB[(j * 16 + m) * 32 + quad * 8];
#pragma unroll
        for (int i = 0; i < 2; i++)
#pragma unroll
            for (int j = 0; j < 2; j++)
                acc[i][j] = __builtin_amdgcn_mfma_f32_16x16x32_bf16(
                    af[i], bfr[j], acc[i][j], 0, 0, 0);
    }

    // epilogue: col(oc)=lane&15, row(n)=quad*4+reg ; add off_b
    float tb[2];
#pragma unroll
    for (int j = 0; j < 2; j++) tb[j] = off_b[j * 16 + m];
#pragma unroll
    for (int i = 0; i < 2; i++)
#pragma unroll
        for (int r = 0; r < 4; r++) {
            long n = n0 + wave * 32 + i * 16 + quad * 4 + r;
#pragma unroll
            for (int j = 0; j < 2; j++)
                off[n * 32 + j * 16 + m] = acc[i][j][r] + tb[j];
        }
}

// ---------------------------------------------------------------------------
// K3: bilinear sampling from bf16 h1 -> S bf16 [n][k], k = kk*96 + c.
// ---------------------------------------------------------------------------
__global__ __launch_bounds__(384) void k3_sample(
    const unsigned short* __restrict__ h1, const float* __restrict__ off,
    unsigned short* __restrict__ S)
{
    const int p = blockIdx.x;     // 0..195
    const int b = blockIdx.y;     // 0..63
    const int y = p / 14, xo = p % 14;
    const int tid = threadIdx.x;
    const int c4 = tid % 24, kk = tid / 24;
    const int kh = kk >> 2, kw = kk & 3;

    const float* ob = off + ((long)(b * 196 + p)) * 32;
    float dy = ob[kk * 2];
    float dx = ob[kk * 2 + 1];

    float py = (float)(y * 4 + kh) + dy;
    float px = (float)(xo * 4 + kw) + dx;
    float y0f = floorf(py), x0f = floorf(px);
    float wy = py - y0f, wx = px - x0f;
    int y0 = (int)y0f, x0 = (int)x0f;
    int y1 = y0 + 1,  x1 = x0 + 1;

    float my0 = (y0 >= 0 && y0 < 56) ? 1.f : 0.f;
    float my1 = (y1 >= 0 && y1 < 56) ? 1.f : 0.f;
    float mx0 = (x0 >= 0 && x0 < 56) ? 1.f : 0.f;
    float mx1 = (x1 >= 0 && x1 < 56) ? 1.f : 0.f;
    int y0c = min(max(y0, 0), 55), y1c = min(max(y1, 0), 55);
    int x0c = min(max(x0, 0), 55), x1c = min(max(x1, 0), 55);

    const unsigned short* hb = h1 + (long)b * 56 * 56 * 96 + c4 * 4;
    ushort4v v00 = *(const ushort4v*)&hb[(y0c * 56 + x0c) * 96];
    ushort4v v01 = *(const ushort4v*)&hb[(y0c * 56 + x1c) * 96];
    ushort4v v10 = *(const ushort4v*)&hb[(y1c * 56 + x0c) * 96];
    ushort4v v11 = *(const ushort4v*)&hb[(y1c * 56 + x1c) * 96];

    float w00 = my0 * mx0 * (1.f - wy) * (1.f - wx);
    float w01 = my0 * mx1 * (1.f - wy) * wx;
    float w10 = my1 * mx0 * wy * (1.f - wx);
    float w11 = my1 * mx1 * wy * wx;

    ushort4v rr;
#pragma unroll
    for (int c = 0; c < 4; c++) {
        float v = bf2f(((unsigned short*)&v00)[c]) * w00
                + bf2f(((unsigned short*)&v01)[c]) * w01
                + bf2f(((unsigned short*)&v10)[c]) * w10
                + bf2f(((unsigned short*)&v11)[c]) * w11;
        ((unsigned short*)&rr)[c] = f2bf(v);
    }

    long n = (long)b * 196 + p;
    *(ushort4v*)&S[n * 1536 + kk * 96 + c4 * 4] = rr;
}

// ---------------------------------------------------------------------------
// K4: bf16 MFMA GEMM  C[n][oc] = S[n][k] * Wtb[oc][k]^T  (N=12544,M=768,K=1536)
// 128x128 tile, BK=32, 4 waves (2x2), each wave 4x4 MFMA 16x16x32 tiles.
// Epilogue: leaky(acc + t2[oc]) -> out (already (B,P,C) layout).
// ---------------------------------------------------------------------------
__global__ __launch_bounds__(256) void k4_gemm_mfma(
    const unsigned short* __restrict__ S,    // [12544][1536] bf16
    const unsigned short* __restrict__ Wtb,  // [768][1536]  bf16 (B^T, scaled)
    const float* __restrict__ t2, float* __restrict__ out)
{
    const int tid  = threadIdx.x;
    const int wave = tid >> 6;
    const int lane = tid & 63;
    const int oc0 = blockIdx.x * 128;
    const int n0  = blockIdx.y * 128;
    const int wr  = wave >> 1, wc = wave & 1;
    const int m    = lane & 15;
    const int quad = lane >> 4;

    __shared__ unsigned short sA[128 * 32];
    __shared__ unsigned short sB[128 * 32];

    const int srow  = wave * 32 + (lane >> 2);
    const int skoff = (lane & 3) * 8;
    const unsigned short* gA0 = S   + (long)(n0  + srow) * 1536 + skoff;
    const unsigned short* gA1 = gA0 + 16L * 1536;
    const unsigned short* gB0 = Wtb + (long)(oc0 + srow) * 1536 + skoff;
    const unsigned short* gB1 = gB0 + 16L * 1536;
    unsigned short* lA0 = &sA[(wave * 32 +  0) * 32];
    unsigned short* lA1 = &sA[(wave * 32 + 16) * 32];
    unsigned short* lB0 = &sB[(wave * 32 +  0) * 32];
    unsigned short* lB1 = &sB[(wave * 32 + 16) * 32];

    floatx4 acc[4][4];
#pragma unroll
    for (int i = 0; i < 4; i++)
#pragma unroll
        for (int j = 0; j < 4; j++) acc[i][j] = (floatx4)0.f;

    for (int kt = 0; kt < 48; ++kt) {
        __syncthreads();
        __builtin_amdgcn_global_load_lds(
            (const __attribute__((address_space(1))) void*)gA0,
            (__attribute__((address_space(3))) void*)lA0, 16, 0, 0);
        __builtin_amdgcn_global_load_lds(
            (const __attribute__((address_space(1))) void*)gA1,
            (__attribute__((address_space(3))) void*)lA1, 16, 0, 0);
        __builtin_amdgcn_global_load_lds(
            (const __attribute__((address_space(1))) void*)gB0,
            (__attribute__((address_space(3))) void*)lB0, 16, 0, 0);
        __builtin_amdgcn_global_load_lds(
            (const __attribute__((address_space(1))) void*)gB1,
            (__attribute__((address_space(3))) void*)lB1, 16, 0, 0);
        gA0 += 32; gA1 += 32; gB0 += 32; gB1 += 32;
        __syncthreads();

        bf16x8 af[4], bf[4];
#pragma unroll
        for (int i = 0; i < 4; i++)
            af[i] = *(const bf16x8*)&sA[(wr * 64 + i * 16 + m) * 32 + quad * 8];
#pragma unroll
        for (int j = 0; j < 4; j++)
            bf[j] = *(const bf16x8*)&sB[(wc * 64 + j * 16 + m) * 32 + quad * 8];
#pragma unroll
        for (int i = 0; i < 4; i++)
#pragma unroll
            for (int j = 0; j < 4; j++)
                acc[i][j] = __builtin_amdgcn_mfma_f32_16x16x32_bf16(
                    af[i], bf[j], acc[i][j], 0, 0, 0);
    }

    float tb[4];
#pragma unroll
    for (int j = 0; j < 4; j++) tb[j] = t2[oc0 + wc * 64 + j * 16 + m];
#pragma unroll
    for (int i = 0; i < 4; i++) {
#pragma unroll
        for (int r = 0; r < 4; r++) {
            long n = n0 + wr * 64 + i * 16 + quad * 4 + r;
            float* orow = out + n * 768 + oc0 + wc * 64 + m;
#pragma unroll
            for (int j = 0; j < 4; j++) {
                float v = acc[i][j][r] + tb[j];
                orow[j * 16] = v >= 0.f ? v : SLOPE * v;
            }
        }
    }
}

// ---------------------------------------------------------------------------
extern "C" void kernel_launch(void* const* d_in, const int* in_sizes, int n_in,
                              void* d_out, int out_size, void* d_ws, size_t ws_size,
                              hipStream_t stream)
{
    const float* x      = (const float*)d_in[0];
    const float* stem_w = (const float*)d_in[1];
    const float* stem_b = (const float*)d_in[2];
    const float* bn1_g  = (const float*)d_in[3];
    const float* bn1_b  = (const float*)d_in[4];
    const float* bn1_m  = (const float*)d_in[5];
    const float* bn1_v  = (const float*)d_in[6];
    const float* off_w  = (const float*)d_in[7];
    const float* off_b  = (const float*)d_in[8];
    const float* dcn_w  = (const float*)d_in[9];
    const float* dcn_b  = (const float*)d_in[10];
    const float* bn2_g  = (const float*)d_in[11];
    const float* bn2_b  = (const float*)d_in[12];
    const float* bn2_m  = (const float*)d_in[13];
    const float* bn2_v  = (const float*)d_in[14];

    float* ws  = (float*)d_ws;        // needs 81.2 MB
    float* out = (float*)d_out;

    unsigned short* h1  = (unsigned short*)(ws + WS_H1B);
    float* off = ws + WS_OFF;
    float* w1t = ws + WS_W1T;
    float* s1  = ws + WS_S1;
    float* t1  = ws + WS_T1;
    float* t2  = ws + WS_T2;
    unsigned short* Sb  = (unsigned short*)(ws + WS_SB);
    unsigned short* Wtb = (unsigned short*)(ws + WS_WTB);
    unsigned short* Wob = (unsigned short*)(ws + WS_WOB);

    k0_prep<<<4823, 256, 0, stream>>>(stem_w, stem_b, bn1_g, bn1_b, bn1_m, bn1_v,
                                      off_w, dcn_w, dcn_b, bn2_g, bn2_b, bn2_m,
                                      bn2_v, ws);
    k1_stem<<<dim3(56, 64), 384, 0, stream>>>(x, w1t, s1, t1, h1);
    k2_mfma<<<98, 256, 0, stream>>>(h1, Wob, off_b, off);
    k3_sample<<<dim3(196, 64), 384, 0, stream>>>(h1, off, Sb);
    k4_gemm_mfma<<<dim3(6, 98), 256, 0, stream>>>(Sb, Wtb, t2, out);
}

// Round 5
// 223.328 us; speedup vs baseline: 3.6633x; 1.1313x over previous
//
#include <hip/hip_runtime.h>

#define EPS   1e-5f
#define SLOPE 0.01f

// ---------------------------------------------------------------------------
// Workspace layout (float offsets). Total 20,287,424 floats = 81.1 MB.
// ---------------------------------------------------------------------------
#define WS_H1B  0L            // h1  bf16 NHWC (64,56,56,96)   (9633792 f)
#define WS_OFF  9633792L      // off f32 [n=12544][32]            401408
#define WS_S1   10035200L     // bn1 scale f32 [96]
#define WS_T1   10035296L     // bn1 bias  f32 [96]
#define WS_T2   10035392L     // fused dcn_b+bn2 bias f32 [768]
#define WS_SB   10036160L     // S   bf16 [n=12544][k=1536]    (9633792 f)
#define WS_WTB  19669952L     // Wtb bf16 [oc=768][k=1536]      (589824 f)
#define WS_WOB  20259776L     // Wob bf16 [oc=32][k=1536]        (24576 f)
#define WS_W1B  20284352L     // W1b bf16 [ks=2][oc=96][kl=32]    (3072 f)

__device__ __forceinline__ unsigned short f2bf(float f) {
    unsigned int u = __builtin_bit_cast(unsigned int, f);
    u += 0x7fffu + ((u >> 16) & 1u);
    return (unsigned short)(u >> 16);
}
__device__ __forceinline__ float bf2f(unsigned short u) {
    unsigned int t = ((unsigned int)u) << 16;
    return __builtin_bit_cast(float, t);
}

typedef __attribute__((ext_vector_type(4))) unsigned short ushort4v;
typedef __attribute__((ext_vector_type(8))) unsigned short ushort8v;
typedef __attribute__((ext_vector_type(8))) short bf16x8;
typedef __attribute__((ext_vector_type(4))) float floatx4;

// ---------------------------------------------------------------------------
// K0: weight prep.
//   Wtb[oc][k] = bf16( dcn_w[oc][c][kk] * inv2[oc] ),  k = kk*96 + c  (B^T)
//   Wob[oc][k] = bf16( off_w[oc][c][khw] ),            k = khw*96 + c (B^T)
//   W1b[ks][oc][kl] = bf16( stem_w[oc][k] ), k = ks*32+kl, zero-pad k>=48
// ---------------------------------------------------------------------------
__global__ __launch_bounds__(256) void k0_prep(
    const float* __restrict__ stem_w, const float* __restrict__ stem_b,
    const float* __restrict__ bn1_g,  const float* __restrict__ bn1_b,
    const float* __restrict__ bn1_m,  const float* __restrict__ bn1_v,
    const float* __restrict__ off_w,  const float* __restrict__ dcn_w,
    const float* __restrict__ dcn_b,  const float* __restrict__ bn2_g,
    const float* __restrict__ bn2_b,  const float* __restrict__ bn2_m,
    const float* __restrict__ bn2_v,  float* __restrict__ ws)
{
    long i = (long)blockIdx.x * 256 + threadIdx.x;
    unsigned short* Wtb = (unsigned short*)(ws + WS_WTB);
    unsigned short* Wob = (unsigned short*)(ws + WS_WOB);
    unsigned short* W1b = (unsigned short*)(ws + WS_W1B);
    if (i < 1179648L) {                       // Wtb (bf16, [oc][k])
        int oc = (int)(i / 1536), k = (int)(i % 1536);
        int kk = k / 96, c = k % 96;
        float inv2 = bn2_g[oc] * rsqrtf(bn2_v[oc] + EPS);
        Wtb[i] = f2bf(dcn_w[oc * 1536 + c * 16 + kk] * inv2);
    } else if (i < 1228800L) {                // Wob (bf16, [oc][k])
        int i2 = (int)(i - 1179648L);
        int oc = i2 / 1536, k = i2 % 1536;
        int khw = k / 96, c = k % 96;
        Wob[i2] = f2bf(off_w[oc * 1536 + c * 16 + khw]);
    } else if (i < 1234944L) {                // W1b (bf16, [2][96][32], pad)
        int i3 = (int)(i - 1228800L);
        int ks = i3 / 3072, rr = i3 % 3072;
        int oc = rr >> 5, kl = rr & 31;
        int k  = ks * 32 + kl;
        W1b[i3] = f2bf(k < 48 ? stem_w[oc * 48 + k] : 0.f);
    } else if (i < 1235040L) {                // s1
        int c = (int)(i - 1234944L);
        ws[WS_S1 + c] = bn1_g[c] * rsqrtf(bn1_v[c] + EPS);
    } else if (i < 1235136L) {                // t1
        int c = (int)(i - 1235040L);
        float s = bn1_g[c] * rsqrtf(bn1_v[c] + EPS);
        ws[WS_T1 + c] = stem_b[c] * s + bn1_b[c] - bn1_m[c] * s;
    } else if (i < 1235904L) {                // t2
        int oc = (int)(i - 1235136L);
        float inv2 = bn2_g[oc] * rsqrtf(bn2_v[oc] + EPS);
        ws[WS_T2 + oc] = dcn_b[oc] * inv2 + bn2_b[oc] - bn2_m[oc] * inv2;
    }
}

// ---------------------------------------------------------------------------
// K1: stem conv as bf16 MFMA GEMM: h1[p][c] = im2col(x)[p][k] * W1b[c][k]^T
// N=200704 pixels, M=96, K=48 (padded 64). stride==kernel => im2col is an
// address permutation of x; threads gather float4, cvt bf16, ds_write.
// 128-pixel tile, 4 waves, each wave 2 rowtiles x 6 octiles x 2 ksteps MFMA.
// Epilogue: bn1 + leaky -> h1 bf16 NHWC.
// ---------------------------------------------------------------------------
__global__ __launch_bounds__(256) void k1_stem_mfma(
    const float* __restrict__ x, const unsigned short* __restrict__ W1b,
    const float* __restrict__ s1, const float* __restrict__ t1,
    unsigned short* __restrict__ h1)
{
    const int tid  = threadIdx.x;
    const int wave = tid >> 6, lane = tid & 63;
    const int m = lane & 15, quad = lane >> 4;
    const int p0 = blockIdx.x * 128;

    __shared__ unsigned short sA[2][128][32];   // [kstep][row][kl], 64 B rows
    __shared__ unsigned short sB[2][96][32];    // flat copy of W1b

    // ---- stage B: 12288 B contiguous, 12 x 1024 B via global_load_lds ----
    {
        unsigned short* sBf = &sB[0][0][0];
#pragma unroll
        for (int i = 0; i < 3; i++) {
            int inst = wave * 3 + i;
            const unsigned short* g = W1b + inst * 512 + lane * 8;
            __builtin_amdgcn_global_load_lds(
                (const __attribute__((address_space(1))) void*)g,
                (__attribute__((address_space(3))) void*)(sBf + inst * 512),
                16, 0, 0);
        }
    }

    // ---- zero-fill pad region sA[1][*][16..31] ----
    {
        int r = tid >> 1, off = 16 + (tid & 1) * 8;
        *(ushort8v*)&sA[1][r][off] = (ushort8v)0;
    }

    // ---- stage A: 1536 chunks (row, ci, kh) of float4 -> bf16x4 ----
#pragma unroll
    for (int i = 0; i < 6; i++) {
        int cid = tid + 256 * i;
        int r = cid / 12, s = cid % 12;
        int ci = s >> 2, kh = s & 3;
        int p = p0 + r;
        int b  = p / 3136, rem = p % 3136;
        int oy = rem / 56, ox = rem % 56;
        float4 v = *(const float4*)&x[((long)((b * 3 + ci) * 224 + oy * 4 + kh)) * 224 + ox * 4];
        ushort4v hv;
        hv.x = f2bf(v.x); hv.y = f2bf(v.y); hv.z = f2bf(v.z); hv.w = f2bf(v.w);
        int k0i = ci * 16 + kh * 4;
        *(ushort4v*)&sA[k0i >> 5][r][k0i & 31] = hv;
    }
    __syncthreads();

    // ---- MFMA: wave owns rows wave*32..+31, all 96 oc ----
    bf16x8 bfv[6][2], af[2][2];
#pragma unroll
    for (int j = 0; j < 6; j++)
#pragma unroll
        for (int ks = 0; ks < 2; ks++)
            bfv[j][ks] = *(const bf16x8*)&sB[ks][j * 16 + m][quad * 8];
#pragma unroll
    for (int rt = 0; rt < 2; rt++)
#pragma unroll
        for (int ks = 0; ks < 2; ks++)
            af[rt][ks] = *(const bf16x8*)&sA[ks][wave * 32 + rt * 16 + m][quad * 8];

    floatx4 acc[2][6];
#pragma unroll
    for (int rt = 0; rt < 2; rt++)
#pragma unroll
        for (int j = 0; j < 6; j++) {
            floatx4 a = (floatx4)0.f;
            a = __builtin_amdgcn_mfma_f32_16x16x32_bf16(af[rt][0], bfv[j][0], a, 0, 0, 0);
            a = __builtin_amdgcn_mfma_f32_16x16x32_bf16(af[rt][1], bfv[j][1], a, 0, 0, 0);
            acc[rt][j] = a;
        }

    // ---- epilogue: bn1 + leaky -> h1 bf16 (col c = j*16+m, row = quad*4+r)
#pragma unroll
    for (int j = 0; j < 6; j++) {
        int c = j * 16 + m;
        float sc = s1[c], bi = t1[c];
#pragma unroll
        for (int rt = 0; rt < 2; rt++)
#pragma unroll
            for (int r = 0; r < 4; r++) {
                long p = p0 + wave * 32 + rt * 16 + quad * 4 + r;
                float v = acc[rt][j][r] * sc + bi;
                v = v >= 0.f ? v : SLOPE * v;
                h1[p * 96 + c] = f2bf(v);
            }
    }
}

// ---------------------------------------------------------------------------
// K2: offset conv as bf16 MFMA GEMM reading im2col rows DIRECTLY from h1.
// off[n][oc] = im2col(h1)[n][k] * Wob[oc][k]^T.  N=12544, M=32, K=1536.
// ---------------------------------------------------------------------------
__global__ __launch_bounds__(256) void k2_mfma(
    const unsigned short* __restrict__ h1,   // bf16 NHWC
    const unsigned short* __restrict__ Wob,  // [32][1536] bf16
    const float* __restrict__ off_b, float* __restrict__ off)
{
    const int tid  = threadIdx.x;
    const int wave = tid >> 6;
    const int lane = tid & 63;
    const int n0   = blockIdx.x * 128;
    const int m    = lane & 15;
    const int quad = lane >> 4;

    __shared__ unsigned short sA[128 * 32];
    __shared__ unsigned short sB[32 * 32];

    const int skoff = (lane & 3) * 8;
    int n_a = n0 + wave * 32 + (lane >> 2);
    int n_b = n_a + 16;
    int ba = n_a / 196, pa = n_a % 196;
    int bb = n_b / 196, pb = n_b % 196;
    long pixa = ((long)(ba * 56 + (pa / 14) * 4) * 56 + (pa % 14) * 4);
    long pixb = ((long)(bb * 56 + (pb / 14) * 4) * 56 + (pb % 14) * 4);

    const unsigned short* gB = Wob + (long)((wave & 1) * 16 + (lane >> 2)) * 1536 + skoff;
    unsigned short* lA0 = &sA[(wave * 32 +  0) * 32];
    unsigned short* lA1 = &sA[(wave * 32 + 16) * 32];
    unsigned short* lB  = &sB[((wave & 1) * 16) * 32];

    floatx4 acc[2][2];
#pragma unroll
    for (int i = 0; i < 2; i++)
#pragma unroll
        for (int j = 0; j < 2; j++) acc[i][j] = (floatx4)0.f;

    for (int kt = 0; kt < 48; ++kt) {
        int khw = kt / 3;
        int c0  = (kt - khw * 3) * 32;
        int kh  = khw >> 2, kw = khw & 3;
        long eoff = (long)(kh * 56 + kw) * 96 + c0 + skoff;
        const unsigned short* gA0 = h1 + pixa * 96 + eoff;
        const unsigned short* gA1 = h1 + pixb * 96 + eoff;

        __syncthreads();
        __builtin_amdgcn_global_load_lds(
            (const __attribute__((address_space(1))) void*)gA0,
            (__attribute__((address_space(3))) void*)lA0, 16, 0, 0);
        __builtin_amdgcn_global_load_lds(
            (const __attribute__((address_space(1))) void*)gA1,
            (__attribute__((address_space(3))) void*)lA1, 16, 0, 0);
        if (wave < 2)
            __builtin_amdgcn_global_load_lds(
                (const __attribute__((address_space(1))) void*)gB,
                (__attribute__((address_space(3))) void*)lB, 16, 0, 0);
        gB += 32;
        __syncthreads();

        bf16x8 af[2], bfr[2];
#pragma unroll
        for (int i = 0; i < 2; i++)
            af[i] = *(const bf16x8*)&sA[(wave * 32 + i * 16 + m) * 32 + quad * 8];
#pragma unroll
        for (int j = 0; j < 2; j++)
            bfr[j] = *(const bf16x8*)&sB[(j * 16 + m) * 32 + quad * 8];
#pragma unroll
        for (int i = 0; i < 2; i++)
#pragma unroll
            for (int j = 0; j < 2; j++)
                acc[i][j] = __builtin_amdgcn_mfma_f32_16x16x32_bf16(
                    af[i], bfr[j], acc[i][j], 0, 0, 0);
    }

    float tb[2];
#pragma unroll
    for (int j = 0; j < 2; j++) tb[j] = off_b[j * 16 + m];
#pragma unroll
    for (int i = 0; i < 2; i++)
#pragma unroll
        for (int r = 0; r < 4; r++) {
            long n = n0 + wave * 32 + i * 16 + quad * 4 + r;
#pragma unroll
            for (int j = 0; j < 2; j++)
                off[n * 32 + j * 16 + m] = acc[i][j][r] + tb[j];
        }
}

// ---------------------------------------------------------------------------
// K3: bilinear sampling from bf16 h1 -> S bf16 [n][k], k = kk*96 + c.
// ---------------------------------------------------------------------------
__global__ __launch_bounds__(384) void k3_sample(
    const unsigned short* __restrict__ h1, const float* __restrict__ off,
    unsigned short* __restrict__ S)
{
    const int p = blockIdx.x;     // 0..195
    const int b = blockIdx.y;     // 0..63
    const int y = p / 14, xo = p % 14;
    const int tid = threadIdx.x;
    const int c4 = tid % 24, kk = tid / 24;
    const int kh = kk >> 2, kw = kk & 3;

    const float* ob = off + ((long)(b * 196 + p)) * 32;
    float dy = ob[kk * 2];
    float dx = ob[kk * 2 + 1];

    float py = (float)(y * 4 + kh) + dy;
    float px = (float)(xo * 4 + kw) + dx;
    float y0f = floorf(py), x0f = floorf(px);
    float wy = py - y0f, wx = px - x0f;
    int y0 = (int)y0f, x0 = (int)x0f;
    int y1 = y0 + 1,  x1 = x0 + 1;

    float my0 = (y0 >= 0 && y0 < 56) ? 1.f : 0.f;
    float my1 = (y1 >= 0 && y1 < 56) ? 1.f : 0.f;
    float mx0 = (x0 >= 0 && x0 < 56) ? 1.f : 0.f;
    float mx1 = (x1 >= 0 && x1 < 56) ? 1.f : 0.f;
    int y0c = min(max(y0, 0), 55), y1c = min(max(y1, 0), 55);
    int x0c = min(max(x0, 0), 55), x1c = min(max(x1, 0), 55);

    const unsigned short* hb = h1 + (long)b * 56 * 56 * 96 + c4 * 4;
    ushort4v v00 = *(const ushort4v*)&hb[(y0c * 56 + x0c) * 96];
    ushort4v v01 = *(const ushort4v*)&hb[(y0c * 56 + x1c) * 96];
    ushort4v v10 = *(const ushort4v*)&hb[(y1c * 56 + x0c) * 96];
    ushort4v v11 = *(const ushort4v*)&hb[(y1c * 56 + x1c) * 96];

    float w00 = my0 * mx0 * (1.f - wy) * (1.f - wx);
    float w01 = my0 * mx1 * (1.f - wy) * wx;
    float w10 = my1 * mx0 * wy * (1.f - wx);
    float w11 = my1 * mx1 * wy * wx;

    ushort4v rr;
#pragma unroll
    for (int c = 0; c < 4; c++) {
        float v = bf2f(((unsigned short*)&v00)[c]) * w00
                + bf2f(((unsigned short*)&v01)[c]) * w01
                + bf2f(((unsigned short*)&v10)[c]) * w10
                + bf2f(((unsigned short*)&v11)[c]) * w11;
        ((unsigned short*)&rr)[c] = f2bf(v);
    }

    long n = (long)b * 196 + p;
    *(ushort4v*)&S[n * 1536 + kk * 96 + c4 * 4] = rr;
}

// ---------------------------------------------------------------------------
// K4: bf16 MFMA GEMM  C[n][oc] = S[n][k] * Wtb[oc][k]^T  (N=12544,M=768,K=1536)
// 128x128 tile, BK=32, 4 waves (2x2), each wave 4x4 MFMA 16x16x32 tiles.
// Epilogue: leaky(acc + t2[oc]) -> out (already (B,P,C) layout).
// ---------------------------------------------------------------------------
__global__ __launch_bounds__(256) void k4_gemm_mfma(
    const unsigned short* __restrict__ S,    // [12544][1536] bf16
    const unsigned short* __restrict__ Wtb,  // [768][1536]  bf16 (B^T, scaled)
    const float* __restrict__ t2, float* __restrict__ out)
{
    const int tid  = threadIdx.x;
    const int wave = tid >> 6;
    const int lane = tid & 63;
    const int oc0 = blockIdx.x * 128;
    const int n0  = blockIdx.y * 128;
    const int wr  = wave >> 1, wc = wave & 1;
    const int m    = lane & 15;
    const int quad = lane >> 4;

    __shared__ unsigned short sA[128 * 32];
    __shared__ unsigned short sB[128 * 32];

    const int srow  = wave * 32 + (lane >> 2);
    const int skoff = (lane & 3) * 8;
    const unsigned short* gA0 = S   + (long)(n0  + srow) * 1536 + skoff;
    const unsigned short* gA1 = gA0 + 16L * 1536;
    const unsigned short* gB0 = Wtb + (long)(oc0 + srow) * 1536 + skoff;
    const unsigned short* gB1 = gB0 + 16L * 1536;
    unsigned short* lA0 = &sA[(wave * 32 +  0) * 32];
    unsigned short* lA1 = &sA[(wave * 32 + 16) * 32];
    unsigned short* lB0 = &sB[(wave * 32 +  0) * 32];
    unsigned short* lB1 = &sB[(wave * 32 + 16) * 32];

    floatx4 acc[4][4];
#pragma unroll
    for (int i = 0; i < 4; i++)
#pragma unroll
        for (int j = 0; j < 4; j++) acc[i][j] = (floatx4)0.f;

    for (int kt = 0; kt < 48; ++kt) {
        __syncthreads();
        __builtin_amdgcn_global_load_lds(
            (const __attribute__((address_space(1))) void*)gA0,
            (__attribute__((address_space(3))) void*)lA0, 16, 0, 0);
        __builtin_amdgcn_global_load_lds(
            (const __attribute__((address_space(1))) void*)gA1,
            (__attribute__((address_space(3))) void*)lA1, 16, 0, 0);
        __builtin_amdgcn_global_load_lds(
            (const __attribute__((address_space(1))) void*)gB0,
            (__attribute__((address_space(3))) void*)lB0, 16, 0, 0);
        __builtin_amdgcn_global_load_lds(
            (const __attribute__((address_space(1))) void*)gB1,
            (__attribute__((address_space(3))) void*)lB1, 16, 0, 0);
        gA0 += 32; gA1 += 32; gB0 += 32; gB1 += 32;
        __syncthreads();

        bf16x8 af[4], bf[4];
#pragma unroll
        for (int i = 0; i < 4; i++)
            af[i] = *(const bf16x8*)&sA[(wr * 64 + i * 16 + m) * 32 + quad * 8];
#pragma unroll
        for (int j = 0; j < 4; j++)
            bf[j] = *(const bf16x8*)&sB[(wc * 64 + j * 16 + m) * 32 + quad * 8];
#pragma unroll
        for (int i = 0; i < 4; i++)
#pragma unroll
            for (int j = 0; j < 4; j++)
                acc[i][j] = __builtin_amdgcn_mfma_f32_16x16x32_bf16(
                    af[i], bf[j], acc[i][j], 0, 0, 0);
    }

    float tb[4];
#pragma unroll
    for (int j = 0; j < 4; j++) tb[j] = t2[oc0 + wc * 64 + j * 16 + m];
#pragma unroll
    for (int i = 0; i < 4; i++) {
#pragma unroll
        for (int r = 0; r < 4; r++) {
            long n = n0 + wr * 64 + i * 16 + quad * 4 + r;
            float* orow = out + n * 768 + oc0 + wc * 64 + m;
#pragma unroll
            for (int j = 0; j < 4; j++) {
                float v = acc[i][j][r] + tb[j];
                orow[j * 16] = v >= 0.f ? v : SLOPE * v;
            }
        }
    }
}

// ---------------------------------------------------------------------------
extern "C" void kernel_launch(void* const* d_in, const int* in_sizes, int n_in,
                              void* d_out, int out_size, void* d_ws, size_t ws_size,
                              hipStream_t stream)
{
    const float* x      = (const float*)d_in[0];
    const float* stem_w = (const float*)d_in[1];
    const float* stem_b = (const float*)d_in[2];
    const float* bn1_g  = (const float*)d_in[3];
    const float* bn1_b  = (const float*)d_in[4];
    const float* bn1_m  = (const float*)d_in[5];
    const float* bn1_v  = (const float*)d_in[6];
    const float* off_w  = (const float*)d_in[7];
    const float* off_b  = (const float*)d_in[8];
    const float* dcn_w  = (const float*)d_in[9];
    const float* dcn_b  = (const float*)d_in[10];
    const float* bn2_g  = (const float*)d_in[11];
    const float* bn2_b  = (const float*)d_in[12];
    const float* bn2_m  = (const float*)d_in[13];
    const float* bn2_v  = (const float*)d_in[14];

    float* ws  = (float*)d_ws;        // needs 81.2 MB
    float* out = (float*)d_out;

    unsigned short* h1  = (unsigned short*)(ws + WS_H1B);
    float* off = ws + WS_OFF;
    float* s1  = ws + WS_S1;
    float* t1  = ws + WS_T1;
    float* t2  = ws + WS_T2;
    unsigned short* Sb  = (unsigned short*)(ws + WS_SB);
    unsigned short* Wtb = (unsigned short*)(ws + WS_WTB);
    unsigned short* Wob = (unsigned short*)(ws + WS_WOB);
    unsigned short* W1b = (unsigned short*)(ws + WS_W1B);

    k0_prep<<<4828, 256, 0, stream>>>(stem_w, stem_b, bn1_g, bn1_b, bn1_m, bn1_v,
                                      off_w, dcn_w, dcn_b, bn2_g, bn2_b, bn2_m,
                                      bn2_v, ws);
    k1_stem_mfma<<<1568, 256, 0, stream>>>(x, W1b, s1, t1, h1);
    k2_mfma<<<98, 256, 0, stream>>>(h1, Wob, off_b, off);
    k3_sample<<<dim3(196, 64), 384, 0, stream>>>(h1, off, Sb);
    k4_gemm_mfma<<<dim3(6, 98), 256, 0, stream>>>(Sb, Wtb, t2, out);
}